// Round 1
// baseline (405.948 us; speedup 1.0000x reference)
//
#include <hip/hip_runtime.h>
#include <hip/hip_bf16.h>

#define DEV static __device__ __forceinline__

typedef short bf16x8_t __attribute__((ext_vector_type(8)));
typedef float f32x4 __attribute__((ext_vector_type(4)));

#define GLDS16(gp, lp) __builtin_amdgcn_global_load_lds( \
    (const __attribute__((address_space(1))) void*)(gp), \
    (__attribute__((address_space(3))) void*)(lp), 16, 0, 0)

DEV int reflect_idx(int q, int L) {
    q = q < 0 ? -q : q;
    q = q >= L ? 2 * L - 2 - q : q;
    return q;
}

DEV unsigned short f2bf(float f) {
    unsigned int b = __float_as_uint(f);
    unsigned int r = (b + 0x7FFFu + ((b >> 16) & 1u)) >> 16;
    return (unsigned short)r;
}
DEV float bf2f(unsigned short u) {
    return __uint_as_float(((unsigned int)u) << 16);
}

// ---------------------------------------------------------------------------
// Fused prep + transpose:
//  - blocks with (y==0,z==0): also convert w1 -> wb [3kk][256co][512ci] bf16,
//    w2 -> w2b [3kk][32co][256ci] bf16, zero lacc[0..127] (loss acc + valid
//    flags + completion counter). Runs in the shadow of the HBM-bound
//    transpose (16 of 8192 blocks do ~102 extra elements each).
//  - all blocks: transpose x[n][512ci][1024t] fp32 -> xb[nr][1024t][512ci] bf16
__global__ __launch_bounds__(256) void kprep_xt(
        const float* __restrict__ x, const float* __restrict__ w1,
        const float* __restrict__ w2, unsigned short* __restrict__ xb,
        unsigned short* __restrict__ wb, unsigned short* __restrict__ w2b,
        float* lacc, int n0) {
    const int tid = threadIdx.x;

    if (blockIdx.y == 0 && blockIdx.z == 0) {
        int g = blockIdx.x * 256 + tid;           // 0..4095
        for (int idx = g; idx < 417792; idx += 4096) {
            if (idx < 393216) {
                int kk = idx >> 17;
                int rem = idx & 131071;
                int co = rem >> 9;
                int ci = rem & 511;
                wb[idx] = f2bf(w1[(co * 512 + ci) * 3 + kk]);
            } else {
                int j = idx - 393216;
                int ci = j & 255;
                int co = (j >> 8) & 31;
                int kk = j >> 13;
                w2b[j] = f2bf(w2[(co * 256 + ci) * 3 + kk]);
            }
        }
        if (g < 128) lacc[g] = 0.0f;
    }

    __shared__ float ls[64][65];
    const int t0 = blockIdx.x * 64, ci0 = blockIdx.y * 64;
    const int n = n0 + blockIdx.z;
    const float* xp = x + ((size_t)n * 512 + ci0) * 1024 + t0;
    for (int idx = tid; idx < 1024; idx += 256) {
        int r = idx >> 4, c4 = (idx & 15) * 4;
        float4 v = *(const float4*)(xp + r * 1024 + c4);
        ls[r][c4] = v.x; ls[r][c4 + 1] = v.y; ls[r][c4 + 2] = v.z; ls[r][c4 + 3] = v.w;
    }
    __syncthreads();
    unsigned short* xo = xb + ((size_t)blockIdx.z * 1024 + t0) * 512 + ci0;
#pragma unroll
    for (int p = 0; p < 2; ++p) {
        int trow = (tid >> 3) + p * 32;
        int cj = (tid & 7) * 8;
        unsigned short pk[8];
#pragma unroll
        for (int j = 0; j < 8; ++j) pk[j] = f2bf(ls[cj + j][trow]);
        *(uint4*)(xo + (size_t)trow * 512 + cj) = *(const uint4*)pk;
    }
}

// ---------------------------------------------------------------------------
// K1 v5 (unchanged): R6's m97-pattern implicit GEMM with BK=64 intervals.
// Block tile 128t x 128co; 24 K-intervals of 64 ci (2 planes of 32), LDS
// double-buffered (2 x 32KB = 64KB), 8 glds + 1 barrier + 32 MFMA/wave per
// interval. kk tap shift applied at staging (reflect). Epilogue aliases LDS.
__global__ __launch_bounds__(256, 2) void k1_mfma(
    const unsigned short* __restrict__ xb, const unsigned short* __restrict__ wb,
    const float* __restrict__ g, const float* __restrict__ be,
    const float* __restrict__ mn, const float* __restrict__ vr,
    unsigned short* __restrict__ y1t, int n0)
{
    const int tid  = threadIdx.x;
    const int lane = tid & 63;
    const int w    = tid >> 6;
    const int tw   = w >> 1;
    const int cw   = w & 1;
    const int tq   = lane & 15;
    const int qd   = lane >> 4;
    const int t0   = blockIdx.x * 128;
    const int nr   = blockIdx.y;
    const int n    = n0 + nr;
    const int cb   = blockIdx.z;

    __shared__ unsigned short smem[32768];   // 65536 B: 2 bufs x (2 planes x (A 4096 + B 4096))

    // staging lane slots (R6-verified swizzle q' = q ^ ((row>>1)&3))
    const int rl0 = tid >> 2;
    const int rl1 = 64 + (tid >> 2);
    const int q0  = (tid & 3) ^ ((rl0 >> 1) & 3);
    const int q1  = (tid & 3) ^ ((rl1 >> 1) & 3);

    const unsigned short* xn = xb + (size_t)nr * 1024 * 512;
    int aoff0[3], aoff1[3];
#pragma unroll
    for (int kk = 0; kk < 3; ++kk) {
        aoff0[kk] = reflect_idx(t0 + rl0 + 8 * kk - 8, 1024) * 512 + q0 * 8;
        aoff1[kk] = reflect_idx(t0 + rl1 + 8 * kk - 8, 1024) * 512 + q1 * 8;
    }
    const unsigned short* wp0 = wb + (size_t)(cb * 128 + rl0) * 512 + q0 * 8;
    const unsigned short* wp1 = wb + (size_t)(cb * 128 + rl1) * 512 + q1 * 8;

    const int atom = qd ^ ((tq >> 1) & 3);

    f32x4 acc[4][4];
#pragma unroll
    for (int a = 0; a < 4; ++a)
#pragma unroll
        for (int b = 0; b < 4; ++b) acc[a][b] = (f32x4){0.f, 0.f, 0.f, 0.f};

    // prologue: stage interval 0 (kk=0, ci 0..63) into buf 0
#pragma unroll
    for (int p = 0; p < 2; ++p) {
        GLDS16(xn + aoff0[0] + p * 32, &smem[p * 8192 + tid * 8]);
        GLDS16(xn + aoff1[0] + p * 32, &smem[p * 8192 + 2048 + tid * 8]);
        GLDS16(wp0 + p * 32, &smem[p * 8192 + 4096 + tid * 8]);
        GLDS16(wp1 + p * 32, &smem[p * 8192 + 6144 + tid * 8]);
    }

#pragma unroll
    for (int c = 0; c < 24; ++c) {
        const int bo = (c & 1) * 16384;
        __syncthreads();   // buf ready (vmcnt0 drain happens here)
        if (c < 23) {
            const int nc = c + 1, nk = nc >> 3, nj = nc & 7;
            const int no = ((c + 1) & 1) * 16384;
#pragma unroll
            for (int p = 0; p < 2; ++p) {
                const int col = nj * 64 + p * 32;
                GLDS16(xn + aoff0[nk] + col, &smem[no + p * 8192 + tid * 8]);
                GLDS16(xn + aoff1[nk] + col, &smem[no + p * 8192 + 2048 + tid * 8]);
                GLDS16(wp0 + (size_t)nk * 131072 + col, &smem[no + p * 8192 + 4096 + tid * 8]);
                GLDS16(wp1 + (size_t)nk * 131072 + col, &smem[no + p * 8192 + 6144 + tid * 8]);
            }
        }
#pragma unroll
        for (int p = 0; p < 2; ++p) {
            const int ab = bo + p * 8192;
            bf16x8_t Af[4], Bf[4];
#pragma unroll
            for (int ts = 0; ts < 4; ++ts)
                Af[ts] = *(const bf16x8_t*)&smem[ab + (tw * 64 + ts * 16 + tq) * 32 + atom * 8];
#pragma unroll
            for (int cs = 0; cs < 4; ++cs)
                Bf[cs] = *(const bf16x8_t*)&smem[ab + 4096 + (cw * 64 + cs * 16 + tq) * 32 + atom * 8];
#pragma unroll
            for (int ts = 0; ts < 4; ++ts)
#pragma unroll
                for (int cs = 0; cs < 4; ++cs)
                    acc[ts][cs] = __builtin_amdgcn_mfma_f32_16x16x32_bf16(
                        Af[ts], Bf[cs], acc[ts][cs], 0, 0, 0);
        }
    }

    // epilogue: bn + relu -> bf16 -> LDS transpose [128t][128co] (stride 136)
    __syncthreads();
#pragma unroll
    for (int cs = 0; cs < 4; ++cs) {
        int col = cw * 64 + cs * 16 + tq;
        int co  = cb * 128 + col;
        float iv = g[co] / sqrtf(vr[co] + 1e-5f);
        float sh = be[co] - mn[co] * iv;
#pragma unroll
        for (int ts = 0; ts < 4; ++ts)
#pragma unroll
            for (int rg = 0; rg < 4; ++rg)
                smem[(tw * 64 + ts * 16 + qd * 4 + rg) * 136 + col] =
                    f2bf(fmaxf(fmaf(acc[ts][cs][rg], iv, sh), 0.0f));
    }
    __syncthreads();
    const int srow = tid >> 4, sseg = tid & 15;
#pragma unroll
    for (int p = 0; p < 8; ++p) {
        int row = p * 16 + srow;
        unsigned short* yp = y1t + ((size_t)n * 1024 + t0 + row) * 256 + cb * 128 + sseg * 8;
        *(uint4*)yp = *(const uint4*)&smem[row * 136 + sseg * 8];
    }
}

// ---------------------------------------------------------------------------
// K2 v2 (unchanged): upsample2(y1t) -> conv2 via bf16 MFMA, ping-pong staging.
// Output TRANSPOSED fp32: y2t[n][2048t][32co].
__global__ __launch_bounds__(256, 2) void k2_mfma(
    const unsigned short* __restrict__ y1t, const unsigned short* __restrict__ w2b,
    const float* __restrict__ g, const float* __restrict__ be,
    const float* __restrict__ mn, const float* __restrict__ vr,
    float* __restrict__ y2t)
{
    const int tid  = threadIdx.x;
    const int lane = tid & 63;
    const int w    = tid >> 6;
    const int tq   = lane & 15;
    const int qd   = lane >> 4;
    const int t0   = blockIdx.x * 256;
    const int n    = blockIdx.y;

    __shared__ union SM {
        unsigned short us[2][288 * 40];   // 46080 B
        float tr[256 * 36];               // 36864 B (aliases, used after final sync)
    } sm;

    f32x4 acc[4][2];
#pragma unroll
    for (int a = 0; a < 4; ++a)
#pragma unroll
        for (int b = 0; b < 2; ++b) acc[a][b] = (f32x4){0.f, 0.f, 0.f, 0.f};

    const unsigned short* yn = y1t + (size_t)n * 1024 * 256;

    auto stage = [&](int ch, int buf) {
        const int ci0 = ch * 32;
        for (int idx = tid; idx < 1152; idx += 256) {
            int r = idx >> 2, gq = idx & 3;
            int u = reflect_idx(t0 - 16 + r, 2048);
            float src = fmaxf((float)u * 0.5f - 0.25f, 0.0f);
            int i0 = (int)src;
            float wl = src - (float)i0;
            int i1 = i0 + 1 > 1023 ? 1023 : i0 + 1;
            const unsigned short* p0 = yn + (size_t)i0 * 256 + ci0 + gq * 8;
            const unsigned short* p1 = yn + (size_t)i1 * 256 + ci0 + gq * 8;
            uint4 ua = *(const uint4*)p0;
            uint4 ub = *(const uint4*)p1;
            const unsigned short* sa = (const unsigned short*)&ua;
            const unsigned short* sb = (const unsigned short*)&ub;
            unsigned short pk[8];
#pragma unroll
            for (int j = 0; j < 8; ++j) {
                float a = bf2f(sa[j]);
                float b = bf2f(sb[j]);
                pk[j] = f2bf(a + wl * (b - a));
            }
            *(uint4*)&sm.us[buf][r * 40 + gq * 8] = *(const uint4*)pk;
        }
    };

    stage(0, 0);
    for (int ch = 0; ch < 8; ++ch) {
        const int buf = ch & 1;
        __syncthreads();   // buf staged; prev chunk's readers of buf^1 done
        if (ch < 7) stage(ch + 1, buf ^ 1);

        const int ci0 = ch * 32;
        bf16x8_t Bf[2][3];
#pragma unroll
        for (int cs = 0; cs < 2; ++cs)
#pragma unroll
            for (int kk = 0; kk < 3; ++kk)
                Bf[cs][kk] = *(const bf16x8_t*)(w2b +
                    ((size_t)(kk * 32 + cs * 16 + tq)) * 256 + ci0 + qd * 8);

        bf16x8_t Af[6];
#pragma unroll
        for (int s = 0; s < 6; ++s)
            Af[s] = *(const bf16x8_t*)&sm.us[buf][(w * 64 + s * 16 + tq) * 40 + qd * 8];

#pragma unroll
        for (int ts = 0; ts < 4; ++ts)
#pragma unroll
            for (int cs = 0; cs < 2; ++cs)
#pragma unroll
                for (int kk = 0; kk < 3; ++kk)
                    acc[ts][cs] = __builtin_amdgcn_mfma_f32_16x16x32_bf16(
                        Af[ts + kk], Bf[cs][kk], acc[ts][cs], 0, 0, 0);
    }

    __syncthreads();
#pragma unroll
    for (int cs = 0; cs < 2; ++cs) {
        int co = cs * 16 + tq;
        float iv = g[co] / sqrtf(vr[co] + 1e-5f);
        float sh = be[co] - mn[co] * iv;
#pragma unroll
        for (int ts = 0; ts < 4; ++ts)
#pragma unroll
            for (int rg = 0; rg < 4; ++rg) {
                int tl = w * 64 + ts * 16 + qd * 4 + rg;
                sm.tr[tl * 36 + co] = fmaxf(fmaf(acc[ts][cs][rg], iv, sh), 0.0f);
            }
    }
    __syncthreads();
    float* yo = y2t + ((size_t)n * 2048 + t0 + tid) * 32;
#pragma unroll
    for (int j = 0; j < 8; ++j)
        *(float4*)(yo + j * 4) = *(const float4*)&sm.tr[tid * 36 + j * 4];
}

// ---------------------------------------------------------------------------
// K3+CE fused: upsample2(y2t) -> conv3 (32->3, d=32) + bias, transposed store;
// then CE partial sum + valid flags from the register-resident x0..x2 (saves
// the k4b read-back pass), one atomic per block, last-block-done finalization
// (saves the k4c dispatch). Device-scope atomics per Guideline 16.
__global__ __launch_bounds__(256, 2) void k3_ce(
    const float* __restrict__ y2t, const float* __restrict__ w3,
    const float* __restrict__ bias, const float* __restrict__ tg,
    float* __restrict__ out, float* lacc)
{
    const int tid = threadIdx.x;
    const int t0 = blockIdx.x * 256;
    const int n  = blockIdx.y;

    __shared__ float us[32 * 321];
    __shared__ float wsh[288];
    __shared__ float wsum[4];
    __shared__ int snz[4];

    for (int idx = tid; idx < 288; idx += 256) wsh[idx] = w3[idx];

    const float* yn = y2t + (size_t)n * 2048 * 32;
    for (int idx = tid; idx < 1280; idx += 256) {
        int r = idx >> 2, gq = idx & 3;
        int u = reflect_idx(t0 - 32 + r, 4096);
        float src = fmaxf((float)u * 0.5f - 0.25f, 0.0f);
        int i0 = (int)src;
        float wl = src - (float)i0;
        int i1 = i0 + 1 > 2047 ? 2047 : i0 + 1;
        const float* p0 = yn + (size_t)i0 * 32 + gq * 8;
        const float* p1 = yn + (size_t)i1 * 32 + gq * 8;
        float4 a0 = *(const float4*)p0;
        float4 a1 = *(const float4*)(p0 + 4);
        float4 b0 = *(const float4*)p1;
        float4 b1 = *(const float4*)(p1 + 4);
        float v[8];
        v[0] = a0.x + wl * (b0.x - a0.x); v[1] = a0.y + wl * (b0.y - a0.y);
        v[2] = a0.z + wl * (b0.z - a0.z); v[3] = a0.w + wl * (b0.w - a0.w);
        v[4] = a1.x + wl * (b1.x - a1.x); v[5] = a1.y + wl * (b1.y - a1.y);
        v[6] = a1.z + wl * (b1.z - a1.z); v[7] = a1.w + wl * (b1.w - a1.w);
#pragma unroll
        for (int j = 0; j < 8; ++j)
            us[(gq * 8 + j) * 321 + r] = v[j];
    }
    __syncthreads();

    float a0 = 0.0f, a1 = 0.0f, a2 = 0.0f;
#pragma unroll 8
    for (int ci = 0; ci < 32; ++ci) {
        float x0 = us[ci * 321 + tid];
        float x1 = us[ci * 321 + tid + 32];
        float x2 = us[ci * 321 + tid + 64];
        a0 = fmaf(wsh[(0 * 32 + ci) * 3 + 0], x0, a0);
        a0 = fmaf(wsh[(0 * 32 + ci) * 3 + 1], x1, a0);
        a0 = fmaf(wsh[(0 * 32 + ci) * 3 + 2], x2, a0);
        a1 = fmaf(wsh[(1 * 32 + ci) * 3 + 0], x0, a1);
        a1 = fmaf(wsh[(1 * 32 + ci) * 3 + 1], x1, a1);
        a1 = fmaf(wsh[(1 * 32 + ci) * 3 + 2], x2, a1);
        a2 = fmaf(wsh[(2 * 32 + ci) * 3 + 0], x0, a2);
        a2 = fmaf(wsh[(2 * 32 + ci) * 3 + 1], x1, a2);
        a2 = fmaf(wsh[(2 * 32 + ci) * 3 + 2], x2, a2);
    }
    int b = n >> 2, s = n & 3;
    int t = t0 + tid;
    size_t ob = ((size_t)(b * 3) * 4096 + t) * 4 + s;
    float x0 = a0 + bias[0];
    float x1 = a1 + bias[1];
    float x2 = a2 + bias[2];
    out[ob]         = x0;
    out[ob + 16384] = x1;
    out[ob + 32768] = x2;

    // CE from registers (identical math to the old k4b pass)
    float mx = fmaxf(x0, fmaxf(x1, x2));
    float e0 = expf(x0 - mx), e1 = expf(x1 - mx), e2 = expf(x2 - mx);
    float lse = mx + logf(e0 + e1 + e2);
    float g0 = tg[ob], g1 = tg[ob + 16384], g2 = tg[ob + 32768];
    float v = g0 * (lse - x0) + g1 * (lse - x1) + g2 * (lse - x2);
    bool nz = (g0 != 0.0f) | (g1 != 0.0f) | (g2 != 0.0f);

    for (int off = 32; off > 0; off >>= 1) v += __shfl_down(v, off);
    unsigned long long m = __ballot(nz);
    int lane = tid & 63, wid = tid >> 6;
    if (lane == 0) { wsum[wid] = v; snz[wid] = (m != 0ull); }
    __syncthreads();
    if (tid == 0) {
        atomicAdd(lacc, wsum[0] + wsum[1] + wsum[2] + wsum[3]);
        if (snz[0] | snz[1] | snz[2] | snz[3])
            atomicOr((int*)lacc + 8 + n, 1);            // n == b*4 + s
        __threadfence();
        int done = atomicAdd((int*)lacc + 120, 1);
        if (done == (int)(gridDim.x * gridDim.y) - 1) {
            __threadfence();
            // atomic reads guarantee L2-coherent values across XCDs
            float sum = atomicAdd(lacc, 0.0f);
            int num = 0;
#pragma unroll
            for (int j = 0; j < 64; ++j)
                num += (atomicOr((int*)lacc + 8 + j, 0) != 0);
            out[786432] = sum / ((float)num * 4096.0f);
        }
    }
}

// ---------------------------------------------------------------------------
extern "C" void kernel_launch(void* const* d_in, const int* in_sizes, int n_in,
                              void* d_out, int out_size, void* d_ws, size_t ws_size,
                              hipStream_t stream) {
    (void)in_sizes; (void)n_in; (void)out_size;
    const float* fusion  = (const float*)d_in[0];
    const float* targets = (const float*)d_in[1];
    const float* w1  = (const float*)d_in[2];
    const float* g1  = (const float*)d_in[3];
    const float* be1 = (const float*)d_in[4];
    const float* mn1 = (const float*)d_in[5];
    const float* vr1 = (const float*)d_in[6];
    const float* w2  = (const float*)d_in[7];
    const float* g2  = (const float*)d_in[8];
    const float* be2 = (const float*)d_in[9];
    const float* mn2 = (const float*)d_in[10];
    const float* vr2 = (const float*)d_in[11];
    const float* w3  = (const float*)d_in[12];
    const float* b3  = (const float*)d_in[13];
    float* out = (float*)d_out;

    char* ws = (char*)d_ws;
    unsigned short* y1t = (unsigned short*)ws;              // 33,554,432 B
    unsigned short* xb  = (unsigned short*)(ws + 33554432); // 16 or 64 MB
    float* y2t = (float*)(ws + 33554432);                   // 16 MB, aliases xb

    const bool single = ws_size >= 101500000ull;
    size_t woff = single ? (33554432ull + 67108864ull) : (33554432ull + 16777216ull);
    unsigned short* wb  = (unsigned short*)(ws + woff);            // 786,432 B
    unsigned short* w2b = (unsigned short*)(ws + woff + 786432);   //  49,152 B
    float* lacc = (float*)(ws + woff + 786432 + 49152);            //     512 B

    if (single) {
        kprep_xt<<<dim3(16, 8, 64), 256, 0, stream>>>(fusion, w1, w2, xb, wb, w2b, lacc, 0);
        k1_mfma<<<dim3(8, 64, 2), 256, 0, stream>>>(xb, wb, g1, be1, mn1, vr1, y1t, 0);
    } else {
        for (int r = 0; r < 4; ++r) {
            kprep_xt<<<dim3(16, 8, 16), 256, 0, stream>>>(fusion, w1, w2, xb, wb, w2b, lacc, r * 16);
            k1_mfma<<<dim3(8, 16, 2), 256, 0, stream>>>(xb, wb, g1, be1, mn1, vr1, y1t, r * 16);
        }
    }
    k2_mfma<<<dim3(8, 64), 256, 0, stream>>>(y1t, w2b, g2, be2, mn2, vr2, y2t);
    k3_ce<<<dim3(16, 64), 256, 0, stream>>>(y2t, w3, b3, targets, out, lacc);
}

// Round 2
// 375.300 us; speedup vs baseline: 1.0817x; 1.0817x over previous
//
#include <hip/hip_runtime.h>
#include <hip/hip_bf16.h>

#define DEV static __device__ __forceinline__

typedef short bf16x8_t __attribute__((ext_vector_type(8)));
typedef float f32x4 __attribute__((ext_vector_type(4)));

#define GLDS16(gp, lp) __builtin_amdgcn_global_load_lds( \
    (const __attribute__((address_space(1))) void*)(gp), \
    (__attribute__((address_space(3))) void*)(lp), 16, 0, 0)

DEV int reflect_idx(int q, int L) {
    q = q < 0 ? -q : q;
    q = q >= L ? 2 * L - 2 - q : q;
    return q;
}

DEV unsigned short f2bf(float f) {
    unsigned int b = __float_as_uint(f);
    unsigned int r = (b + 0x7FFFu + ((b >> 16) & 1u)) >> 16;
    return (unsigned short)r;
}
DEV float bf2f(unsigned short u) {
    return __uint_as_float(((unsigned int)u) << 16);
}

// ---------------------------------------------------------------------------
// Fused prep + transpose (v2):
//  - weight conversion spread across ALL blocks, <=1 element per thread
//    (no straggler blocks; gated on n0==0 so it runs once).
//  - transpose x[n][512ci][1024t] fp32 -> xb[nr][1024t][512ci] bf16, with
//    all 4 global loads register-staged before LDS stores (guaranteed MLP).
__global__ __launch_bounds__(256) void kprep_xt(
        const float* __restrict__ x, const float* __restrict__ w1,
        const float* __restrict__ w2, unsigned short* __restrict__ xb,
        unsigned short* __restrict__ wb, unsigned short* __restrict__ w2b,
        float* lacc, int n0) {
    const int tid = threadIdx.x;

    if (n0 == 0) {
        int bid = (blockIdx.z * gridDim.y + blockIdx.y) * gridDim.x + blockIdx.x;
        int g = bid * 256 + tid;
        if (g < 393216) {
            int kk = g >> 17;
            int rem = g & 131071;
            int co = rem >> 9;
            int ci = rem & 511;
            wb[g] = f2bf(w1[(co * 512 + ci) * 3 + kk]);
        } else if (g < 417792) {
            int j = g - 393216;
            int ci = j & 255;
            int co = (j >> 8) & 31;
            int kk = j >> 13;
            w2b[j] = f2bf(w2[(co * 256 + ci) * 3 + kk]);
        }
        if (g < 128) lacc[g] = 0.0f;
    }

    __shared__ float ls[64][65];
    const int t0 = blockIdx.x * 64, ci0 = blockIdx.y * 64;
    const int n = n0 + blockIdx.z;
    const float* xp = x + ((size_t)n * 512 + ci0) * 1024 + t0;

    float4 v[4];
#pragma unroll
    for (int i = 0; i < 4; ++i) {
        int idx = tid + i * 256;
        int r = idx >> 4, c4 = (idx & 15) * 4;
        v[i] = *(const float4*)(xp + r * 1024 + c4);
    }
#pragma unroll
    for (int i = 0; i < 4; ++i) {
        int idx = tid + i * 256;
        int r = idx >> 4, c4 = (idx & 15) * 4;
        ls[r][c4] = v[i].x; ls[r][c4 + 1] = v[i].y;
        ls[r][c4 + 2] = v[i].z; ls[r][c4 + 3] = v[i].w;
    }
    __syncthreads();
    unsigned short* xo = xb + ((size_t)blockIdx.z * 1024 + t0) * 512 + ci0;
#pragma unroll
    for (int p = 0; p < 2; ++p) {
        int trow = (tid >> 3) + p * 32;
        int cj = (tid & 7) * 8;
        unsigned short pk[8];
#pragma unroll
        for (int j = 0; j < 8; ++j) pk[j] = f2bf(ls[cj + j][trow]);
        *(uint4*)(xo + (size_t)trow * 512 + cj) = *(const uint4*)pk;
    }
}

// ---------------------------------------------------------------------------
// K1 v5 (unchanged): R6's m97-pattern implicit GEMM with BK=64 intervals.
// Block tile 128t x 128co; 24 K-intervals of 64 ci (2 planes of 32), LDS
// double-buffered (2 x 32KB = 64KB), 8 glds + 1 barrier + 32 MFMA/wave per
// interval. kk tap shift applied at staging (reflect). Epilogue aliases LDS.
__global__ __launch_bounds__(256, 2) void k1_mfma(
    const unsigned short* __restrict__ xb, const unsigned short* __restrict__ wb,
    const float* __restrict__ g, const float* __restrict__ be,
    const float* __restrict__ mn, const float* __restrict__ vr,
    unsigned short* __restrict__ y1t, int n0)
{
    const int tid  = threadIdx.x;
    const int lane = tid & 63;
    const int w    = tid >> 6;
    const int tw   = w >> 1;
    const int cw   = w & 1;
    const int tq   = lane & 15;
    const int qd   = lane >> 4;
    const int t0   = blockIdx.x * 128;
    const int nr   = blockIdx.y;
    const int n    = n0 + nr;
    const int cb   = blockIdx.z;

    __shared__ unsigned short smem[32768];   // 65536 B: 2 bufs x (2 planes x (A 4096 + B 4096))

    // staging lane slots (R6-verified swizzle q' = q ^ ((row>>1)&3))
    const int rl0 = tid >> 2;
    const int rl1 = 64 + (tid >> 2);
    const int q0  = (tid & 3) ^ ((rl0 >> 1) & 3);
    const int q1  = (tid & 3) ^ ((rl1 >> 1) & 3);

    const unsigned short* xn = xb + (size_t)nr * 1024 * 512;
    int aoff0[3], aoff1[3];
#pragma unroll
    for (int kk = 0; kk < 3; ++kk) {
        aoff0[kk] = reflect_idx(t0 + rl0 + 8 * kk - 8, 1024) * 512 + q0 * 8;
        aoff1[kk] = reflect_idx(t0 + rl1 + 8 * kk - 8, 1024) * 512 + q1 * 8;
    }
    const unsigned short* wp0 = wb + (size_t)(cb * 128 + rl0) * 512 + q0 * 8;
    const unsigned short* wp1 = wb + (size_t)(cb * 128 + rl1) * 512 + q1 * 8;

    const int atom = qd ^ ((tq >> 1) & 3);

    f32x4 acc[4][4];
#pragma unroll
    for (int a = 0; a < 4; ++a)
#pragma unroll
        for (int b = 0; b < 4; ++b) acc[a][b] = (f32x4){0.f, 0.f, 0.f, 0.f};

    // prologue: stage interval 0 (kk=0, ci 0..63) into buf 0
#pragma unroll
    for (int p = 0; p < 2; ++p) {
        GLDS16(xn + aoff0[0] + p * 32, &smem[p * 8192 + tid * 8]);
        GLDS16(xn + aoff1[0] + p * 32, &smem[p * 8192 + 2048 + tid * 8]);
        GLDS16(wp0 + p * 32, &smem[p * 8192 + 4096 + tid * 8]);
        GLDS16(wp1 + p * 32, &smem[p * 8192 + 6144 + tid * 8]);
    }

#pragma unroll
    for (int c = 0; c < 24; ++c) {
        const int bo = (c & 1) * 16384;
        __syncthreads();   // buf ready (vmcnt0 drain happens here)
        if (c < 23) {
            const int nc = c + 1, nk = nc >> 3, nj = nc & 7;
            const int no = ((c + 1) & 1) * 16384;
#pragma unroll
            for (int p = 0; p < 2; ++p) {
                const int col = nj * 64 + p * 32;
                GLDS16(xn + aoff0[nk] + col, &smem[no + p * 8192 + tid * 8]);
                GLDS16(xn + aoff1[nk] + col, &smem[no + p * 8192 + 2048 + tid * 8]);
                GLDS16(wp0 + (size_t)nk * 131072 + col, &smem[no + p * 8192 + 4096 + tid * 8]);
                GLDS16(wp1 + (size_t)nk * 131072 + col, &smem[no + p * 8192 + 6144 + tid * 8]);
            }
        }
#pragma unroll
        for (int p = 0; p < 2; ++p) {
            const int ab = bo + p * 8192;
            bf16x8_t Af[4], Bf[4];
#pragma unroll
            for (int ts = 0; ts < 4; ++ts)
                Af[ts] = *(const bf16x8_t*)&smem[ab + (tw * 64 + ts * 16 + tq) * 32 + atom * 8];
#pragma unroll
            for (int cs = 0; cs < 4; ++cs)
                Bf[cs] = *(const bf16x8_t*)&smem[ab + 4096 + (cw * 64 + cs * 16 + tq) * 32 + atom * 8];
#pragma unroll
            for (int ts = 0; ts < 4; ++ts)
#pragma unroll
                for (int cs = 0; cs < 4; ++cs)
                    acc[ts][cs] = __builtin_amdgcn_mfma_f32_16x16x32_bf16(
                        Af[ts], Bf[cs], acc[ts][cs], 0, 0, 0);
        }
    }

    // epilogue: bn + relu -> bf16 -> LDS transpose [128t][128co] (stride 136)
    __syncthreads();
#pragma unroll
    for (int cs = 0; cs < 4; ++cs) {
        int col = cw * 64 + cs * 16 + tq;
        int co  = cb * 128 + col;
        float iv = g[co] / sqrtf(vr[co] + 1e-5f);
        float sh = be[co] - mn[co] * iv;
#pragma unroll
        for (int ts = 0; ts < 4; ++ts)
#pragma unroll
            for (int rg = 0; rg < 4; ++rg)
                smem[(tw * 64 + ts * 16 + qd * 4 + rg) * 136 + col] =
                    f2bf(fmaxf(fmaf(acc[ts][cs][rg], iv, sh), 0.0f));
    }
    __syncthreads();
    const int srow = tid >> 4, sseg = tid & 15;
#pragma unroll
    for (int p = 0; p < 8; ++p) {
        int row = p * 16 + srow;
        unsigned short* yp = y1t + ((size_t)n * 1024 + t0 + row) * 256 + cb * 128 + sseg * 8;
        *(uint4*)yp = *(const uint4*)&smem[row * 136 + sseg * 8];
    }
}

// ---------------------------------------------------------------------------
// K2 v2 (unchanged): upsample2(y1t) -> conv2 via bf16 MFMA, ping-pong staging.
// Output TRANSPOSED fp32: y2t[n][2048t][32co].
__global__ __launch_bounds__(256, 2) void k2_mfma(
    const unsigned short* __restrict__ y1t, const unsigned short* __restrict__ w2b,
    const float* __restrict__ g, const float* __restrict__ be,
    const float* __restrict__ mn, const float* __restrict__ vr,
    float* __restrict__ y2t)
{
    const int tid  = threadIdx.x;
    const int lane = tid & 63;
    const int w    = tid >> 6;
    const int tq   = lane & 15;
    const int qd   = lane >> 4;
    const int t0   = blockIdx.x * 256;
    const int n    = blockIdx.y;

    __shared__ union SM {
        unsigned short us[2][288 * 40];   // 46080 B
        float tr[256 * 36];               // 36864 B (aliases, used after final sync)
    } sm;

    f32x4 acc[4][2];
#pragma unroll
    for (int a = 0; a < 4; ++a)
#pragma unroll
        for (int b = 0; b < 2; ++b) acc[a][b] = (f32x4){0.f, 0.f, 0.f, 0.f};

    const unsigned short* yn = y1t + (size_t)n * 1024 * 256;

    auto stage = [&](int ch, int buf) {
        const int ci0 = ch * 32;
        for (int idx = tid; idx < 1152; idx += 256) {
            int r = idx >> 2, gq = idx & 3;
            int u = reflect_idx(t0 - 16 + r, 2048);
            float src = fmaxf((float)u * 0.5f - 0.25f, 0.0f);
            int i0 = (int)src;
            float wl = src - (float)i0;
            int i1 = i0 + 1 > 1023 ? 1023 : i0 + 1;
            const unsigned short* p0 = yn + (size_t)i0 * 256 + ci0 + gq * 8;
            const unsigned short* p1 = yn + (size_t)i1 * 256 + ci0 + gq * 8;
            uint4 ua = *(const uint4*)p0;
            uint4 ub = *(const uint4*)p1;
            const unsigned short* sa = (const unsigned short*)&ua;
            const unsigned short* sb = (const unsigned short*)&ub;
            unsigned short pk[8];
#pragma unroll
            for (int j = 0; j < 8; ++j) {
                float a = bf2f(sa[j]);
                float b = bf2f(sb[j]);
                pk[j] = f2bf(a + wl * (b - a));
            }
            *(uint4*)&sm.us[buf][r * 40 + gq * 8] = *(const uint4*)pk;
        }
    };

    stage(0, 0);
    for (int ch = 0; ch < 8; ++ch) {
        const int buf = ch & 1;
        __syncthreads();   // buf staged; prev chunk's readers of buf^1 done
        if (ch < 7) stage(ch + 1, buf ^ 1);

        const int ci0 = ch * 32;
        bf16x8_t Bf[2][3];
#pragma unroll
        for (int cs = 0; cs < 2; ++cs)
#pragma unroll
            for (int kk = 0; kk < 3; ++kk)
                Bf[cs][kk] = *(const bf16x8_t*)(w2b +
                    ((size_t)(kk * 32 + cs * 16 + tq)) * 256 + ci0 + qd * 8);

        bf16x8_t Af[6];
#pragma unroll
        for (int s = 0; s < 6; ++s)
            Af[s] = *(const bf16x8_t*)&sm.us[buf][(w * 64 + s * 16 + tq) * 40 + qd * 8];

#pragma unroll
        for (int ts = 0; ts < 4; ++ts)
#pragma unroll
            for (int cs = 0; cs < 2; ++cs)
#pragma unroll
                for (int kk = 0; kk < 3; ++kk)
                    acc[ts][cs] = __builtin_amdgcn_mfma_f32_16x16x32_bf16(
                        Af[ts + kk], Bf[cs][kk], acc[ts][cs], 0, 0, 0);
    }

    __syncthreads();
#pragma unroll
    for (int cs = 0; cs < 2; ++cs) {
        int co = cs * 16 + tq;
        float iv = g[co] / sqrtf(vr[co] + 1e-5f);
        float sh = be[co] - mn[co] * iv;
#pragma unroll
        for (int ts = 0; ts < 4; ++ts)
#pragma unroll
            for (int rg = 0; rg < 4; ++rg) {
                int tl = w * 64 + ts * 16 + qd * 4 + rg;
                sm.tr[tl * 36 + co] = fmaxf(fmaf(acc[ts][cs][rg], iv, sh), 0.0f);
            }
    }
    __syncthreads();
    float* yo = y2t + ((size_t)n * 2048 + t0 + tid) * 32;
#pragma unroll
    for (int j = 0; j < 8; ++j)
        *(float4*)(yo + j * 4) = *(const float4*)&sm.tr[tid * 36 + j * 4];
}

// ---------------------------------------------------------------------------
// K3+CE fused (v2): upsample2(y2t) -> conv3 (32->3, d=32) + bias, transposed
// store; CE partial sum + valid flags from register-resident x0..x2; one
// atomic per block; last-block finalization PARALLELIZED (64 threads read
// the 64 valid flags concurrently instead of 64 serial atomics from tid 0).
__global__ __launch_bounds__(256, 2) void k3_ce(
    const float* __restrict__ y2t, const float* __restrict__ w3,
    const float* __restrict__ bias, const float* __restrict__ tg,
    float* __restrict__ out, float* lacc)
{
    const int tid = threadIdx.x;
    const int t0 = blockIdx.x * 256;
    const int n  = blockIdx.y;

    __shared__ float us[32 * 321];
    __shared__ float wsh[288];
    __shared__ float wsum[4];
    __shared__ int snz[4];
    __shared__ int sdone;

    for (int idx = tid; idx < 288; idx += 256) wsh[idx] = w3[idx];

    const float* yn = y2t + (size_t)n * 2048 * 32;
    for (int idx = tid; idx < 1280; idx += 256) {
        int r = idx >> 2, gq = idx & 3;
        int u = reflect_idx(t0 - 32 + r, 4096);
        float src = fmaxf((float)u * 0.5f - 0.25f, 0.0f);
        int i0 = (int)src;
        float wl = src - (float)i0;
        int i1 = i0 + 1 > 2047 ? 2047 : i0 + 1;
        const float* p0 = yn + (size_t)i0 * 32 + gq * 8;
        const float* p1 = yn + (size_t)i1 * 32 + gq * 8;
        float4 a0 = *(const float4*)p0;
        float4 a1 = *(const float4*)(p0 + 4);
        float4 b0 = *(const float4*)p1;
        float4 b1 = *(const float4*)(p1 + 4);
        float v[8];
        v[0] = a0.x + wl * (b0.x - a0.x); v[1] = a0.y + wl * (b0.y - a0.y);
        v[2] = a0.z + wl * (b0.z - a0.z); v[3] = a0.w + wl * (b0.w - a0.w);
        v[4] = a1.x + wl * (b1.x - a1.x); v[5] = a1.y + wl * (b1.y - a1.y);
        v[6] = a1.z + wl * (b1.z - a1.z); v[7] = a1.w + wl * (b1.w - a1.w);
#pragma unroll
        for (int j = 0; j < 8; ++j)
            us[(gq * 8 + j) * 321 + r] = v[j];
    }
    __syncthreads();

    float a0 = 0.0f, a1 = 0.0f, a2 = 0.0f;
#pragma unroll 8
    for (int ci = 0; ci < 32; ++ci) {
        float x0 = us[ci * 321 + tid];
        float x1 = us[ci * 321 + tid + 32];
        float x2 = us[ci * 321 + tid + 64];
        a0 = fmaf(wsh[(0 * 32 + ci) * 3 + 0], x0, a0);
        a0 = fmaf(wsh[(0 * 32 + ci) * 3 + 1], x1, a0);
        a0 = fmaf(wsh[(0 * 32 + ci) * 3 + 2], x2, a0);
        a1 = fmaf(wsh[(1 * 32 + ci) * 3 + 0], x0, a1);
        a1 = fmaf(wsh[(1 * 32 + ci) * 3 + 1], x1, a1);
        a1 = fmaf(wsh[(1 * 32 + ci) * 3 + 2], x2, a1);
        a2 = fmaf(wsh[(2 * 32 + ci) * 3 + 0], x0, a2);
        a2 = fmaf(wsh[(2 * 32 + ci) * 3 + 1], x1, a2);
        a2 = fmaf(wsh[(2 * 32 + ci) * 3 + 2], x2, a2);
    }
    int b = n >> 2, s = n & 3;
    int t = t0 + tid;
    size_t ob = ((size_t)(b * 3) * 4096 + t) * 4 + s;
    float x0 = a0 + bias[0];
    float x1 = a1 + bias[1];
    float x2 = a2 + bias[2];
    out[ob]         = x0;
    out[ob + 16384] = x1;
    out[ob + 32768] = x2;

    // CE from registers (identical math to the old k4b pass)
    float mx = fmaxf(x0, fmaxf(x1, x2));
    float e0 = expf(x0 - mx), e1 = expf(x1 - mx), e2 = expf(x2 - mx);
    float lse = mx + logf(e0 + e1 + e2);
    float g0 = tg[ob], g1 = tg[ob + 16384], g2 = tg[ob + 32768];
    float v = g0 * (lse - x0) + g1 * (lse - x1) + g2 * (lse - x2);
    bool nz = (g0 != 0.0f) | (g1 != 0.0f) | (g2 != 0.0f);

    for (int off = 32; off > 0; off >>= 1) v += __shfl_down(v, off);
    unsigned long long m = __ballot(nz);
    int lane = tid & 63, wid = tid >> 6;
    if (lane == 0) { wsum[wid] = v; snz[wid] = (m != 0ull); }
    __syncthreads();
    if (tid == 0) {
        atomicAdd(lacc, wsum[0] + wsum[1] + wsum[2] + wsum[3]);
        if (snz[0] | snz[1] | snz[2] | snz[3])
            atomicOr((int*)lacc + 8 + n, 1);            // n == b*4 + s
        __threadfence();
        int done = atomicAdd((int*)lacc + 120, 1);
        sdone = (done == (int)(gridDim.x * gridDim.y) - 1) ? 1 : 0;
    }
    __syncthreads();
    if (sdone) {
        // All other blocks' fenced writes are visible (we observed their
        // counter increments). 64 parallel atomic flag reads, wave-0 ballot.
        if (tid < 64) {
            int fv = (atomicOr((int*)lacc + 8 + tid, 0) != 0) ? 1 : 0;
            unsigned long long fm = __ballot(fv);
            if (tid == 0) {
                float sum = atomicAdd(lacc, 0.0f);
                int num = __popcll(fm);
                out[786432] = sum / ((float)num * 4096.0f);
            }
        }
    }
}

// ---------------------------------------------------------------------------
extern "C" void kernel_launch(void* const* d_in, const int* in_sizes, int n_in,
                              void* d_out, int out_size, void* d_ws, size_t ws_size,
                              hipStream_t stream) {
    (void)in_sizes; (void)n_in; (void)out_size;
    const float* fusion  = (const float*)d_in[0];
    const float* targets = (const float*)d_in[1];
    const float* w1  = (const float*)d_in[2];
    const float* g1  = (const float*)d_in[3];
    const float* be1 = (const float*)d_in[4];
    const float* mn1 = (const float*)d_in[5];
    const float* vr1 = (const float*)d_in[6];
    const float* w2  = (const float*)d_in[7];
    const float* g2  = (const float*)d_in[8];
    const float* be2 = (const float*)d_in[9];
    const float* mn2 = (const float*)d_in[10];
    const float* vr2 = (const float*)d_in[11];
    const float* w3  = (const float*)d_in[12];
    const float* b3  = (const float*)d_in[13];
    float* out = (float*)d_out;

    char* ws = (char*)d_ws;
    unsigned short* y1t = (unsigned short*)ws;              // 33,554,432 B
    unsigned short* xb  = (unsigned short*)(ws + 33554432); // 16 or 64 MB
    float* y2t = (float*)(ws + 33554432);                   // 16 MB, aliases xb

    const bool single = ws_size >= 101500000ull;
    size_t woff = single ? (33554432ull + 67108864ull) : (33554432ull + 16777216ull);
    unsigned short* wb  = (unsigned short*)(ws + woff);            // 786,432 B
    unsigned short* w2b = (unsigned short*)(ws + woff + 786432);   //  49,152 B
    float* lacc = (float*)(ws + woff + 786432 + 49152);            //     512 B

    if (single) {
        kprep_xt<<<dim3(16, 8, 64), 256, 0, stream>>>(fusion, w1, w2, xb, wb, w2b, lacc, 0);
        k1_mfma<<<dim3(8, 64, 2), 256, 0, stream>>>(xb, wb, g1, be1, mn1, vr1, y1t, 0);
    } else {
        for (int r = 0; r < 4; ++r) {
            kprep_xt<<<dim3(16, 8, 16), 256, 0, stream>>>(fusion, w1, w2, xb, wb, w2b, lacc, r * 16);
            k1_mfma<<<dim3(8, 16, 2), 256, 0, stream>>>(xb, wb, g1, be1, mn1, vr1, y1t, r * 16);
        }
    }
    k2_mfma<<<dim3(8, 64), 256, 0, stream>>>(y1t, w2b, g2, be2, mn2, vr2, y2t);
    k3_ce<<<dim3(16, 64), 256, 0, stream>>>(y2t, w3, b3, targets, out, lacc);
}

// Round 4
// 351.123 us; speedup vs baseline: 1.1561x; 1.0689x over previous
//
#include <hip/hip_runtime.h>
#include <hip/hip_bf16.h>

#define DEV static __device__ __forceinline__

typedef short bf16x8_t __attribute__((ext_vector_type(8)));
typedef float f32x4 __attribute__((ext_vector_type(4)));

#define GLDS16(gp, lp) __builtin_amdgcn_global_load_lds( \
    (const __attribute__((address_space(1))) void*)(gp), \
    (__attribute__((address_space(3))) void*)(lp), 16, 0, 0)

DEV int reflect_idx(int q, int L) {
    q = q < 0 ? -q : q;
    q = q >= L ? 2 * L - 2 - q : q;
    return q;
}

DEV unsigned short f2bf(float f) {
    unsigned int b = __float_as_uint(f);
    unsigned int r = (b + 0x7FFFu + ((b >> 16) & 1u)) >> 16;
    return (unsigned short)r;
}
DEV float bf2f(unsigned short u) {
    return __uint_as_float(((unsigned int)u) << 16);
}

// ---------------------------------------------------------------------------
// Fused prep + transpose (v2, proven in R2):
//  - weight conversion spread across ALL blocks, <=1 element per thread.
//  - transpose x[n][512ci][1024t] fp32 -> xb[nr][1024t][512ci] bf16, with
//    all 4 global loads register-staged before LDS stores.
__global__ __launch_bounds__(256) void kprep_xt(
        const float* __restrict__ x, const float* __restrict__ w1,
        const float* __restrict__ w2, unsigned short* __restrict__ xb,
        unsigned short* __restrict__ wb, unsigned short* __restrict__ w2b,
        float* lacc, int n0) {
    const int tid = threadIdx.x;

    if (n0 == 0) {
        int bid = (blockIdx.z * gridDim.y + blockIdx.y) * gridDim.x + blockIdx.x;
        int g = bid * 256 + tid;
        if (g < 393216) {
            int kk = g >> 17;
            int rem = g & 131071;
            int co = rem >> 9;
            int ci = rem & 511;
            wb[g] = f2bf(w1[(co * 512 + ci) * 3 + kk]);
        } else if (g < 417792) {
            int j = g - 393216;
            int ci = j & 255;
            int co = (j >> 8) & 31;
            int kk = j >> 13;
            w2b[j] = f2bf(w2[(co * 256 + ci) * 3 + kk]);
        }
        if (g < 128) lacc[g] = 0.0f;
    }

    __shared__ float ls[64][65];
    const int t0 = blockIdx.x * 64, ci0 = blockIdx.y * 64;
    const int n = n0 + blockIdx.z;
    const float* xp = x + ((size_t)n * 512 + ci0) * 1024 + t0;

    float4 v[4];
#pragma unroll
    for (int i = 0; i < 4; ++i) {
        int idx = tid + i * 256;
        int r = idx >> 4, c4 = (idx & 15) * 4;
        v[i] = *(const float4*)(xp + r * 1024 + c4);
    }
#pragma unroll
    for (int i = 0; i < 4; ++i) {
        int idx = tid + i * 256;
        int r = idx >> 4, c4 = (idx & 15) * 4;
        ls[r][c4] = v[i].x; ls[r][c4 + 1] = v[i].y;
        ls[r][c4 + 2] = v[i].z; ls[r][c4 + 3] = v[i].w;
    }
    __syncthreads();
    unsigned short* xo = xb + ((size_t)blockIdx.z * 1024 + t0) * 512 + ci0;
#pragma unroll
    for (int p = 0; p < 2; ++p) {
        int trow = (tid >> 3) + p * 32;
        int cj = (tid & 7) * 8;
        unsigned short pk[8];
#pragma unroll
        for (int j = 0; j < 8; ++j) pk[j] = f2bf(ls[cj + j][trow]);
        *(uint4*)(xo + (size_t)trow * 512 + cj) = *(const uint4*)pk;
    }
}

// ---------------------------------------------------------------------------
// K1 v5 (REVERTED to the proven R0/R2 structure after v6's pipeline failed
// correctness): m97-pattern implicit GEMM, BK=64 intervals, 128t x 128co
// block tile, LDS double-buffered (2 x 32KB), __syncthreads per interval
// (vmcnt0 drain at barrier -- known ~20% structural cost, but HW-verified
// correct). kk tap shift applied at staging (reflect). Epilogue aliases LDS.
__global__ __launch_bounds__(256, 2) void k1_mfma(
    const unsigned short* __restrict__ xb, const unsigned short* __restrict__ wb,
    const float* __restrict__ g, const float* __restrict__ be,
    const float* __restrict__ mn, const float* __restrict__ vr,
    unsigned short* __restrict__ y1t, int n0)
{
    const int tid  = threadIdx.x;
    const int lane = tid & 63;
    const int w    = tid >> 6;
    const int tw   = w >> 1;
    const int cw   = w & 1;
    const int tq   = lane & 15;
    const int qd   = lane >> 4;
    const int t0   = blockIdx.x * 128;
    const int nr   = blockIdx.y;
    const int n    = n0 + nr;
    const int cb   = blockIdx.z;

    __shared__ unsigned short smem[32768];   // 65536 B: 2 bufs x (2 planes x (A 4096 + B 4096))

    // staging lane slots (R6-verified swizzle q' = q ^ ((row>>1)&3))
    const int rl0 = tid >> 2;
    const int rl1 = 64 + (tid >> 2);
    const int q0  = (tid & 3) ^ ((rl0 >> 1) & 3);
    const int q1  = (tid & 3) ^ ((rl1 >> 1) & 3);

    const unsigned short* xn = xb + (size_t)nr * 1024 * 512;
    int aoff0[3], aoff1[3];
#pragma unroll
    for (int kk = 0; kk < 3; ++kk) {
        aoff0[kk] = reflect_idx(t0 + rl0 + 8 * kk - 8, 1024) * 512 + q0 * 8;
        aoff1[kk] = reflect_idx(t0 + rl1 + 8 * kk - 8, 1024) * 512 + q1 * 8;
    }
    const unsigned short* wp0 = wb + (size_t)(cb * 128 + rl0) * 512 + q0 * 8;
    const unsigned short* wp1 = wb + (size_t)(cb * 128 + rl1) * 512 + q1 * 8;

    const int atom = qd ^ ((tq >> 1) & 3);

    f32x4 acc[4][4];
#pragma unroll
    for (int a = 0; a < 4; ++a)
#pragma unroll
        for (int b = 0; b < 4; ++b) acc[a][b] = (f32x4){0.f, 0.f, 0.f, 0.f};

    // prologue: stage interval 0 (kk=0, ci 0..63) into buf 0
#pragma unroll
    for (int p = 0; p < 2; ++p) {
        GLDS16(xn + aoff0[0] + p * 32, &smem[p * 8192 + tid * 8]);
        GLDS16(xn + aoff1[0] + p * 32, &smem[p * 8192 + 2048 + tid * 8]);
        GLDS16(wp0 + p * 32, &smem[p * 8192 + 4096 + tid * 8]);
        GLDS16(wp1 + p * 32, &smem[p * 8192 + 6144 + tid * 8]);
    }

#pragma unroll
    for (int c = 0; c < 24; ++c) {
        const int bo = (c & 1) * 16384;
        __syncthreads();   // buf ready (vmcnt0 drain happens here)
        if (c < 23) {
            const int nc = c + 1, nk = nc >> 3, nj = nc & 7;
            const int no = ((c + 1) & 1) * 16384;
#pragma unroll
            for (int p = 0; p < 2; ++p) {
                const int col = nj * 64 + p * 32;
                GLDS16(xn + aoff0[nk] + col, &smem[no + p * 8192 + tid * 8]);
                GLDS16(xn + aoff1[nk] + col, &smem[no + p * 8192 + 2048 + tid * 8]);
                GLDS16(wp0 + (size_t)nk * 131072 + col, &smem[no + p * 8192 + 4096 + tid * 8]);
                GLDS16(wp1 + (size_t)nk * 131072 + col, &smem[no + p * 8192 + 6144 + tid * 8]);
            }
        }
#pragma unroll
        for (int p = 0; p < 2; ++p) {
            const int ab = bo + p * 8192;
            bf16x8_t Af[4], Bf[4];
#pragma unroll
            for (int ts = 0; ts < 4; ++ts)
                Af[ts] = *(const bf16x8_t*)&smem[ab + (tw * 64 + ts * 16 + tq) * 32 + atom * 8];
#pragma unroll
            for (int cs = 0; cs < 4; ++cs)
                Bf[cs] = *(const bf16x8_t*)&smem[ab + 4096 + (cw * 64 + cs * 16 + tq) * 32 + atom * 8];
#pragma unroll
            for (int ts = 0; ts < 4; ++ts)
#pragma unroll
                for (int cs = 0; cs < 4; ++cs)
                    acc[ts][cs] = __builtin_amdgcn_mfma_f32_16x16x32_bf16(
                        Af[ts], Bf[cs], acc[ts][cs], 0, 0, 0);
        }
    }

    // epilogue: bn + relu -> bf16 -> LDS transpose [128t][128co] (stride 136)
    __syncthreads();
#pragma unroll
    for (int cs = 0; cs < 4; ++cs) {
        int col = cw * 64 + cs * 16 + tq;
        int co  = cb * 128 + col;
        float iv = g[co] / sqrtf(vr[co] + 1e-5f);
        float sh = be[co] - mn[co] * iv;
#pragma unroll
        for (int ts = 0; ts < 4; ++ts)
#pragma unroll
            for (int rg = 0; rg < 4; ++rg)
                smem[(tw * 64 + ts * 16 + qd * 4 + rg) * 136 + col] =
                    f2bf(fmaxf(fmaf(acc[ts][cs][rg], iv, sh), 0.0f));
    }
    __syncthreads();
    const int srow = tid >> 4, sseg = tid & 15;
#pragma unroll
    for (int p = 0; p < 8; ++p) {
        int row = p * 16 + srow;
        unsigned short* yp = y1t + ((size_t)n * 1024 + t0 + row) * 256 + cb * 128 + sseg * 8;
        *(uint4*)yp = *(const uint4*)&smem[row * 136 + sseg * 8];
    }
}

// ---------------------------------------------------------------------------
// K2 v2 (unchanged): upsample2(y1t) -> conv2 via bf16 MFMA, ping-pong staging.
// Output TRANSPOSED fp32: y2t[n][2048t][32co].
__global__ __launch_bounds__(256, 2) void k2_mfma(
    const unsigned short* __restrict__ y1t, const unsigned short* __restrict__ w2b,
    const float* __restrict__ g, const float* __restrict__ be,
    const float* __restrict__ mn, const float* __restrict__ vr,
    float* __restrict__ y2t)
{
    const int tid  = threadIdx.x;
    const int lane = tid & 63;
    const int w    = tid >> 6;
    const int tq   = lane & 15;
    const int qd   = lane >> 4;
    const int t0   = blockIdx.x * 256;
    const int n    = blockIdx.y;

    __shared__ union SM {
        unsigned short us[2][288 * 40];   // 46080 B
        float tr[256 * 36];               // 36864 B (aliases, used after final sync)
    } sm;

    f32x4 acc[4][2];
#pragma unroll
    for (int a = 0; a < 4; ++a)
#pragma unroll
        for (int b = 0; b < 2; ++b) acc[a][b] = (f32x4){0.f, 0.f, 0.f, 0.f};

    const unsigned short* yn = y1t + (size_t)n * 1024 * 256;

    auto stage = [&](int ch, int buf) {
        const int ci0 = ch * 32;
        for (int idx = tid; idx < 1152; idx += 256) {
            int r = idx >> 2, gq = idx & 3;
            int u = reflect_idx(t0 - 16 + r, 2048);
            float src = fmaxf((float)u * 0.5f - 0.25f, 0.0f);
            int i0 = (int)src;
            float wl = src - (float)i0;
            int i1 = i0 + 1 > 1023 ? 1023 : i0 + 1;
            const unsigned short* p0 = yn + (size_t)i0 * 256 + ci0 + gq * 8;
            const unsigned short* p1 = yn + (size_t)i1 * 256 + ci0 + gq * 8;
            uint4 ua = *(const uint4*)p0;
            uint4 ub = *(const uint4*)p1;
            const unsigned short* sa = (const unsigned short*)&ua;
            const unsigned short* sb = (const unsigned short*)&ub;
            unsigned short pk[8];
#pragma unroll
            for (int j = 0; j < 8; ++j) {
                float a = bf2f(sa[j]);
                float b = bf2f(sb[j]);
                pk[j] = f2bf(a + wl * (b - a));
            }
            *(uint4*)&sm.us[buf][r * 40 + gq * 8] = *(const uint4*)pk;
        }
    };

    stage(0, 0);
    for (int ch = 0; ch < 8; ++ch) {
        const int buf = ch & 1;
        __syncthreads();   // buf staged; prev chunk's readers of buf^1 done
        if (ch < 7) stage(ch + 1, buf ^ 1);

        const int ci0 = ch * 32;
        bf16x8_t Bf[2][3];
#pragma unroll
        for (int cs = 0; cs < 2; ++cs)
#pragma unroll
            for (int kk = 0; kk < 3; ++kk)
                Bf[cs][kk] = *(const bf16x8_t*)(w2b +
                    ((size_t)(kk * 32 + cs * 16 + tq)) * 256 + ci0 + qd * 8);

        bf16x8_t Af[6];
#pragma unroll
        for (int s = 0; s < 6; ++s)
            Af[s] = *(const bf16x8_t*)&sm.us[buf][(w * 64 + s * 16 + tq) * 40 + qd * 8];

#pragma unroll
        for (int ts = 0; ts < 4; ++ts)
#pragma unroll
            for (int cs = 0; cs < 2; ++cs)
#pragma unroll
                for (int kk = 0; kk < 3; ++kk)
                    acc[ts][cs] = __builtin_amdgcn_mfma_f32_16x16x32_bf16(
                        Af[ts + kk], Bf[cs][kk], acc[ts][cs], 0, 0, 0);
    }

    __syncthreads();
#pragma unroll
    for (int cs = 0; cs < 2; ++cs) {
        int co = cs * 16 + tq;
        float iv = g[co] / sqrtf(vr[co] + 1e-5f);
        float sh = be[co] - mn[co] * iv;
#pragma unroll
        for (int ts = 0; ts < 4; ++ts)
#pragma unroll
            for (int rg = 0; rg < 4; ++rg) {
                int tl = w * 64 + ts * 16 + qd * 4 + rg;
                sm.tr[tl * 36 + co] = fmaxf(fmaf(acc[ts][cs][rg], iv, sh), 0.0f);
            }
    }
    __syncthreads();
    float* yo = y2t + ((size_t)n * 2048 + t0 + tid) * 32;
#pragma unroll
    for (int j = 0; j < 8; ++j)
        *(float4*)(yo + j * 4) = *(const float4*)&sm.tr[tid * 36 + j * 4];
}

// ---------------------------------------------------------------------------
// K3+CE fused (v3): upsample2(y2t) -> conv3 + bias, transposed store; CE
// partial sum + valid flags from register-resident x0..x2. NO threadfence /
// done-counter (R2's per-block device-scope fence = L2 writeback x1024 was
// the +18us regression); finalization is a separate 1-block kernel, which
// gets cross-XCD ordering free from the dispatch boundary.
__global__ __launch_bounds__(256, 2) void k3_ce(
    const float* __restrict__ y2t, const float* __restrict__ w3,
    const float* __restrict__ bias, const float* __restrict__ tg,
    float* __restrict__ out, float* lacc)
{
    const int tid = threadIdx.x;
    const int t0 = blockIdx.x * 256;
    const int n  = blockIdx.y;

    __shared__ float us[32 * 321];
    __shared__ float wsh[288];
    __shared__ float wsum[4];
    __shared__ int snz[4];

    for (int idx = tid; idx < 288; idx += 256) wsh[idx] = w3[idx];

    const float* yn = y2t + (size_t)n * 2048 * 32;
    for (int idx = tid; idx < 1280; idx += 256) {
        int r = idx >> 2, gq = idx & 3;
        int u = reflect_idx(t0 - 32 + r, 4096);
        float src = fmaxf((float)u * 0.5f - 0.25f, 0.0f);
        int i0 = (int)src;
        float wl = src - (float)i0;
        int i1 = i0 + 1 > 2047 ? 2047 : i0 + 1;
        const float* p0 = yn + (size_t)i0 * 32 + gq * 8;
        const float* p1 = yn + (size_t)i1 * 32 + gq * 8;
        float4 a0 = *(const float4*)p0;
        float4 a1 = *(const float4*)(p0 + 4);
        float4 b0 = *(const float4*)p1;
        float4 b1 = *(const float4*)(p1 + 4);
        float v[8];
        v[0] = a0.x + wl * (b0.x - a0.x); v[1] = a0.y + wl * (b0.y - a0.y);
        v[2] = a0.z + wl * (b0.z - a0.z); v[3] = a0.w + wl * (b0.w - a0.w);
        v[4] = a1.x + wl * (b1.x - a1.x); v[5] = a1.y + wl * (b1.y - a1.y);
        v[6] = a1.z + wl * (b1.z - a1.z); v[7] = a1.w + wl * (b1.w - a1.w);
#pragma unroll
        for (int j = 0; j < 8; ++j)
            us[(gq * 8 + j) * 321 + r] = v[j];
    }
    __syncthreads();

    float a0 = 0.0f, a1 = 0.0f, a2 = 0.0f;
#pragma unroll 8
    for (int ci = 0; ci < 32; ++ci) {
        float x0 = us[ci * 321 + tid];
        float x1 = us[ci * 321 + tid + 32];
        float x2 = us[ci * 321 + tid + 64];
        a0 = fmaf(wsh[(0 * 32 + ci) * 3 + 0], x0, a0);
        a0 = fmaf(wsh[(0 * 32 + ci) * 3 + 1], x1, a0);
        a0 = fmaf(wsh[(0 * 32 + ci) * 3 + 2], x2, a0);
        a1 = fmaf(wsh[(1 * 32 + ci) * 3 + 0], x0, a1);
        a1 = fmaf(wsh[(1 * 32 + ci) * 3 + 1], x1, a1);
        a1 = fmaf(wsh[(1 * 32 + ci) * 3 + 2], x2, a1);
        a2 = fmaf(wsh[(2 * 32 + ci) * 3 + 0], x0, a2);
        a2 = fmaf(wsh[(2 * 32 + ci) * 3 + 1], x1, a2);
        a2 = fmaf(wsh[(2 * 32 + ci) * 3 + 2], x2, a2);
    }
    int b = n >> 2, s = n & 3;
    int t = t0 + tid;
    size_t ob = ((size_t)(b * 3) * 4096 + t) * 4 + s;
    float x0 = a0 + bias[0];
    float x1 = a1 + bias[1];
    float x2 = a2 + bias[2];
    out[ob]         = x0;
    out[ob + 16384] = x1;
    out[ob + 32768] = x2;

    // CE from registers (identical math to the original k4b pass)
    float mx = fmaxf(x0, fmaxf(x1, x2));
    float e0 = expf(x0 - mx), e1 = expf(x1 - mx), e2 = expf(x2 - mx);
    float lse = mx + logf(e0 + e1 + e2);
    float g0 = tg[ob], g1 = tg[ob + 16384], g2 = tg[ob + 32768];
    float v = g0 * (lse - x0) + g1 * (lse - x1) + g2 * (lse - x2);
    bool nz = (g0 != 0.0f) | (g1 != 0.0f) | (g2 != 0.0f);

    for (int off = 32; off > 0; off >>= 1) v += __shfl_down(v, off);
    unsigned long long m = __ballot(nz);
    int lane = tid & 63, wid = tid >> 6;
    if (lane == 0) { wsum[wid] = v; snz[wid] = (m != 0ull); }
    __syncthreads();
    if (tid == 0) {
        atomicAdd(lacc, wsum[0] + wsum[1] + wsum[2] + wsum[3]);
        if (snz[0] | snz[1] | snz[2] | snz[3])
            atomicOr((int*)lacc + 8 + n, 1);            // n == b*4 + s
    }
}

// K4c: loss = sum / (num_valid * T)  (separate dispatch = free global sync)
__global__ void k4c_final(const float* lacc, float* out) {
    if (threadIdx.x == 0) {
        float sum = lacc[0];
        const int* vf = (const int*)lacc + 8;
        int num = 0;
#pragma unroll
        for (int j = 0; j < 64; ++j) num += (vf[j] != 0);
        out[786432] = sum / ((float)num * 4096.0f);
    }
}

// ---------------------------------------------------------------------------
extern "C" void kernel_launch(void* const* d_in, const int* in_sizes, int n_in,
                              void* d_out, int out_size, void* d_ws, size_t ws_size,
                              hipStream_t stream) {
    (void)in_sizes; (void)n_in; (void)out_size;
    const float* fusion  = (const float*)d_in[0];
    const float* targets = (const float*)d_in[1];
    const float* w1  = (const float*)d_in[2];
    const float* g1  = (const float*)d_in[3];
    const float* be1 = (const float*)d_in[4];
    const float* mn1 = (const float*)d_in[5];
    const float* vr1 = (const float*)d_in[6];
    const float* w2  = (const float*)d_in[7];
    const float* g2  = (const float*)d_in[8];
    const float* be2 = (const float*)d_in[9];
    const float* mn2 = (const float*)d_in[10];
    const float* vr2 = (const float*)d_in[11];
    const float* w3  = (const float*)d_in[12];
    const float* b3  = (const float*)d_in[13];
    float* out = (float*)d_out;

    char* ws = (char*)d_ws;
    unsigned short* y1t = (unsigned short*)ws;              // 33,554,432 B
    unsigned short* xb  = (unsigned short*)(ws + 33554432); // 16 or 64 MB
    float* y2t = (float*)(ws + 33554432);                   // 16 MB, aliases xb

    const bool single = ws_size >= 101500000ull;
    size_t woff = single ? (33554432ull + 67108864ull) : (33554432ull + 16777216ull);
    unsigned short* wb  = (unsigned short*)(ws + woff);            // 786,432 B
    unsigned short* w2b = (unsigned short*)(ws + woff + 786432);   //  49,152 B
    float* lacc = (float*)(ws + woff + 786432 + 49152);            //     512 B

    if (single) {
        kprep_xt<<<dim3(16, 8, 64), 256, 0, stream>>>(fusion, w1, w2, xb, wb, w2b, lacc, 0);
        k1_mfma<<<dim3(8, 64, 2), 256, 0, stream>>>(xb, wb, g1, be1, mn1, vr1, y1t, 0);
    } else {
        for (int r = 0; r < 4; ++r) {
            kprep_xt<<<dim3(16, 8, 16), 256, 0, stream>>>(fusion, w1, w2, xb, wb, w2b, lacc, r * 16);
            k1_mfma<<<dim3(8, 16, 2), 256, 0, stream>>>(xb, wb, g1, be1, mn1, vr1, y1t, r * 16);
        }
    }
    k2_mfma<<<dim3(8, 64), 256, 0, stream>>>(y1t, w2b, g2, be2, mn2, vr2, y2t);
    k3_ce<<<dim3(16, 64), 256, 0, stream>>>(y2t, w3, b3, targets, out, lacc);
    k4c_final<<<1, 64, 0, stream>>>(lacc, out);
}

// Round 5
// 342.799 us; speedup vs baseline: 1.1842x; 1.0243x over previous
//
#include <hip/hip_runtime.h>
#include <hip/hip_bf16.h>

#define DEV static __device__ __forceinline__

typedef short bf16x8_t __attribute__((ext_vector_type(8)));
typedef float f32x4 __attribute__((ext_vector_type(4)));

#define GLDS16(gp, lp) __builtin_amdgcn_global_load_lds( \
    (const __attribute__((address_space(1))) void*)(gp), \
    (__attribute__((address_space(3))) void*)(lp), 16, 0, 0)

DEV int reflect_idx(int q, int L) {
    q = q < 0 ? -q : q;
    q = q >= L ? 2 * L - 2 - q : q;
    return q;
}

DEV unsigned short f2bf(float f) {
    unsigned int b = __float_as_uint(f);
    unsigned int r = (b + 0x7FFFu + ((b >> 16) & 1u)) >> 16;
    return (unsigned short)r;
}
DEV float bf2f(unsigned short u) {
    return __uint_as_float(((unsigned int)u) << 16);
}

// ---------------------------------------------------------------------------
// Fused prep + transpose (v2, proven in R2/R4):
//  - weight conversion spread across ALL blocks, <=1 element per thread.
//  - transpose x[n][512ci][1024t] fp32 -> xb[nr][1024t][512ci] bf16, with
//    all 4 global loads register-staged before LDS stores.
__global__ __launch_bounds__(256) void kprep_xt(
        const float* __restrict__ x, const float* __restrict__ w1,
        const float* __restrict__ w2, unsigned short* __restrict__ xb,
        unsigned short* __restrict__ wb, unsigned short* __restrict__ w2b,
        float* lacc, int n0) {
    const int tid = threadIdx.x;

    if (n0 == 0) {
        int bid = (blockIdx.z * gridDim.y + blockIdx.y) * gridDim.x + blockIdx.x;
        int g = bid * 256 + tid;
        if (g < 393216) {
            int kk = g >> 17;
            int rem = g & 131071;
            int co = rem >> 9;
            int ci = rem & 511;
            wb[g] = f2bf(w1[(co * 512 + ci) * 3 + kk]);
        } else if (g < 417792) {
            int j = g - 393216;
            int ci = j & 255;
            int co = (j >> 8) & 31;
            int kk = j >> 13;
            w2b[j] = f2bf(w2[(co * 256 + ci) * 3 + kk]);
        }
        if (g < 128) lacc[g] = 0.0f;
    }

    __shared__ float ls[64][65];
    const int t0 = blockIdx.x * 64, ci0 = blockIdx.y * 64;
    const int n = n0 + blockIdx.z;
    const float* xp = x + ((size_t)n * 512 + ci0) * 1024 + t0;

    float4 v[4];
#pragma unroll
    for (int i = 0; i < 4; ++i) {
        int idx = tid + i * 256;
        int r = idx >> 4, c4 = (idx & 15) * 4;
        v[i] = *(const float4*)(xp + r * 1024 + c4);
    }
#pragma unroll
    for (int i = 0; i < 4; ++i) {
        int idx = tid + i * 256;
        int r = idx >> 4, c4 = (idx & 15) * 4;
        ls[r][c4] = v[i].x; ls[r][c4 + 1] = v[i].y;
        ls[r][c4 + 2] = v[i].z; ls[r][c4 + 3] = v[i].w;
    }
    __syncthreads();
    unsigned short* xo = xb + ((size_t)blockIdx.z * 1024 + t0) * 512 + ci0;
#pragma unroll
    for (int p = 0; p < 2; ++p) {
        int trow = (tid >> 3) + p * 32;
        int cj = (tid & 7) * 8;
        unsigned short pk[8];
#pragma unroll
        for (int j = 0; j < 8; ++j) pk[j] = f2bf(ls[cj + j][trow]);
        *(uint4*)(xo + (size_t)trow * 512 + cj) = *(const uint4*)pk;
    }
}

// ---------------------------------------------------------------------------
// K1 v7: same PROVEN sync protocol as v5 (__syncthreads drain per interval,
// dbuf, issue next interval right after the barrier), but:
//  - BK=32 (48 intervals), dbuf = 2 x 16KB -> LDS 34KB -> 4 blocks/CU
//    (R4 counters: MfmaUtil 20%, Occ 21%, HBM 28% = latency-bound at
//    2 blocks/CU; doubling resident blocks doubles stall-filling work).
//  - cb folded into blockIdx.x so the two blocks sharing an A-tile are
//    8 dispatch-ids apart -> same XCD (id%8) -> A-tile shared in that
//    XCD's L2 (R4 FETCH=198MB = 3x A; pure re-fetch).
__global__ __launch_bounds__(256, 4) void k1_mfma(
    const unsigned short* __restrict__ xb, const unsigned short* __restrict__ wb,
    const float* __restrict__ g, const float* __restrict__ be,
    const float* __restrict__ mn, const float* __restrict__ vr,
    unsigned short* __restrict__ y1t, int n0)
{
    const int tid  = threadIdx.x;
    const int lane = tid & 63;
    const int w    = tid >> 6;
    const int tw   = w >> 1;
    const int cw   = w & 1;
    const int tq   = lane & 15;
    const int qd   = lane >> 4;
    const int t0   = (blockIdx.x & 7) * 128;
    const int cb   = blockIdx.x >> 3;
    const int nr   = blockIdx.y;
    const int n    = n0 + nr;

    __shared__ unsigned short smem[17408];   // loop: 2 bufs x 8192; epilogue: [128][136]

    // staging lane slots (R6-verified swizzle q' = q ^ ((row>>1)&3))
    const int rl0 = tid >> 2;
    const int rl1 = 64 + (tid >> 2);
    const int q0  = (tid & 3) ^ ((rl0 >> 1) & 3);
    const int q1  = (tid & 3) ^ ((rl1 >> 1) & 3);

    const unsigned short* xn = xb + (size_t)nr * 1024 * 512;
    int aoff0[3], aoff1[3];
#pragma unroll
    for (int kk = 0; kk < 3; ++kk) {
        aoff0[kk] = reflect_idx(t0 + rl0 + 8 * kk - 8, 1024) * 512 + q0 * 8;
        aoff1[kk] = reflect_idx(t0 + rl1 + 8 * kk - 8, 1024) * 512 + q1 * 8;
    }
    const unsigned short* wp0 = wb + (size_t)(cb * 128 + rl0) * 512 + q0 * 8;
    const unsigned short* wp1 = wb + (size_t)(cb * 128 + rl1) * 512 + q1 * 8;

    const int atom = qd ^ ((tq >> 1) & 3);

    f32x4 acc[4][4];
#pragma unroll
    for (int a = 0; a < 4; ++a)
#pragma unroll
        for (int b = 0; b < 4; ++b) acc[a][b] = (f32x4){0.f, 0.f, 0.f, 0.f};

    // interval i: kk tap = i>>4, ci chunk = (i&15)*32, buffer = i&1
#define K1_ISSUE(i) do { \
    const int kk_ = (i) >> 4; const int col_ = ((i) & 15) * 32; \
    const int bo_ = ((i) & 1) * 8192; \
    GLDS16(xn + aoff0[kk_] + col_, &smem[bo_ + tid * 8]); \
    GLDS16(xn + aoff1[kk_] + col_, &smem[bo_ + 2048 + tid * 8]); \
    GLDS16(wp0 + (size_t)kk_ * 131072 + col_, &smem[bo_ + 4096 + tid * 8]); \
    GLDS16(wp1 + (size_t)kk_ * 131072 + col_, &smem[bo_ + 6144 + tid * 8]); \
} while (0)

    // prologue: stage interval 0 into buf 0
    K1_ISSUE(0);

#pragma unroll
    for (int c = 0; c < 48; ++c) {
        __syncthreads();   // buf ready (vmcnt0 drain happens here) — v5 protocol
        if (c < 47) K1_ISSUE(c + 1);
        const int ab = (c & 1) * 8192;
        bf16x8_t Af[4], Bf[4];
#pragma unroll
        for (int ts = 0; ts < 4; ++ts)
            Af[ts] = *(const bf16x8_t*)&smem[ab + (tw * 64 + ts * 16 + tq) * 32 + atom * 8];
#pragma unroll
        for (int cs = 0; cs < 4; ++cs)
            Bf[cs] = *(const bf16x8_t*)&smem[ab + 4096 + (cw * 64 + cs * 16 + tq) * 32 + atom * 8];
#pragma unroll
        for (int ts = 0; ts < 4; ++ts)
#pragma unroll
            for (int cs = 0; cs < 4; ++cs)
                acc[ts][cs] = __builtin_amdgcn_mfma_f32_16x16x32_bf16(
                    Af[ts], Bf[cs], acc[ts][cs], 0, 0, 0);
    }
#undef K1_ISSUE

    // epilogue: bn + relu -> bf16 -> LDS transpose [128t][128co] (stride 136)
    __syncthreads();
#pragma unroll
    for (int cs = 0; cs < 4; ++cs) {
        int col = cw * 64 + cs * 16 + tq;
        int co  = cb * 128 + col;
        float iv = g[co] / sqrtf(vr[co] + 1e-5f);
        float sh = be[co] - mn[co] * iv;
#pragma unroll
        for (int ts = 0; ts < 4; ++ts)
#pragma unroll
            for (int rg = 0; rg < 4; ++rg)
                smem[(tw * 64 + ts * 16 + qd * 4 + rg) * 136 + col] =
                    f2bf(fmaxf(fmaf(acc[ts][cs][rg], iv, sh), 0.0f));
    }
    __syncthreads();
    const int srow = tid >> 4, sseg = tid & 15;
#pragma unroll
    for (int p = 0; p < 8; ++p) {
        int row = p * 16 + srow;
        unsigned short* yp = y1t + ((size_t)n * 1024 + t0 + row) * 256 + cb * 128 + sseg * 8;
        *(uint4*)yp = *(const uint4*)&smem[row * 136 + sseg * 8];
    }
}

// ---------------------------------------------------------------------------
// K2 v2 (unchanged): upsample2(y1t) -> conv2 via bf16 MFMA, ping-pong staging.
// Output TRANSPOSED fp32: y2t[n][2048t][32co].
__global__ __launch_bounds__(256, 2) void k2_mfma(
    const unsigned short* __restrict__ y1t, const unsigned short* __restrict__ w2b,
    const float* __restrict__ g, const float* __restrict__ be,
    const float* __restrict__ mn, const float* __restrict__ vr,
    float* __restrict__ y2t)
{
    const int tid  = threadIdx.x;
    const int lane = tid & 63;
    const int w    = tid >> 6;
    const int tq   = lane & 15;
    const int qd   = lane >> 4;
    const int t0   = blockIdx.x * 256;
    const int n    = blockIdx.y;

    __shared__ union SM {
        unsigned short us[2][288 * 40];   // 46080 B
        float tr[256 * 36];               // 36864 B (aliases, used after final sync)
    } sm;

    f32x4 acc[4][2];
#pragma unroll
    for (int a = 0; a < 4; ++a)
#pragma unroll
        for (int b = 0; b < 2; ++b) acc[a][b] = (f32x4){0.f, 0.f, 0.f, 0.f};

    const unsigned short* yn = y1t + (size_t)n * 1024 * 256;

    auto stage = [&](int ch, int buf) {
        const int ci0 = ch * 32;
        for (int idx = tid; idx < 1152; idx += 256) {
            int r = idx >> 2, gq = idx & 3;
            int u = reflect_idx(t0 - 16 + r, 2048);
            float src = fmaxf((float)u * 0.5f - 0.25f, 0.0f);
            int i0 = (int)src;
            float wl = src - (float)i0;
            int i1 = i0 + 1 > 1023 ? 1023 : i0 + 1;
            const unsigned short* p0 = yn + (size_t)i0 * 256 + ci0 + gq * 8;
            const unsigned short* p1 = yn + (size_t)i1 * 256 + ci0 + gq * 8;
            uint4 ua = *(const uint4*)p0;
            uint4 ub = *(const uint4*)p1;
            const unsigned short* sa = (const unsigned short*)&ua;
            const unsigned short* sb = (const unsigned short*)&ub;
            unsigned short pk[8];
#pragma unroll
            for (int j = 0; j < 8; ++j) {
                float a = bf2f(sa[j]);
                float b = bf2f(sb[j]);
                pk[j] = f2bf(a + wl * (b - a));
            }
            *(uint4*)&sm.us[buf][r * 40 + gq * 8] = *(const uint4*)pk;
        }
    };

    stage(0, 0);
    for (int ch = 0; ch < 8; ++ch) {
        const int buf = ch & 1;
        __syncthreads();   // buf staged; prev chunk's readers of buf^1 done
        if (ch < 7) stage(ch + 1, buf ^ 1);

        const int ci0 = ch * 32;
        bf16x8_t Bf[2][3];
#pragma unroll
        for (int cs = 0; cs < 2; ++cs)
#pragma unroll
            for (int kk = 0; kk < 3; ++kk)
                Bf[cs][kk] = *(const bf16x8_t*)(w2b +
                    ((size_t)(kk * 32 + cs * 16 + tq)) * 256 + ci0 + qd * 8);

        bf16x8_t Af[6];
#pragma unroll
        for (int s = 0; s < 6; ++s)
            Af[s] = *(const bf16x8_t*)&sm.us[buf][(w * 64 + s * 16 + tq) * 40 + qd * 8];

#pragma unroll
        for (int ts = 0; ts < 4; ++ts)
#pragma unroll
            for (int cs = 0; cs < 2; ++cs)
#pragma unroll
                for (int kk = 0; kk < 3; ++kk)
                    acc[ts][cs] = __builtin_amdgcn_mfma_f32_16x16x32_bf16(
                        Af[ts + kk], Bf[cs][kk], acc[ts][cs], 0, 0, 0);
    }

    __syncthreads();
#pragma unroll
    for (int cs = 0; cs < 2; ++cs) {
        int co = cs * 16 + tq;
        float iv = g[co] / sqrtf(vr[co] + 1e-5f);
        float sh = be[co] - mn[co] * iv;
#pragma unroll
        for (int ts = 0; ts < 4; ++ts)
#pragma unroll
            for (int rg = 0; rg < 4; ++rg) {
                int tl = w * 64 + ts * 16 + qd * 4 + rg;
                sm.tr[tl * 36 + co] = fmaxf(fmaf(acc[ts][cs][rg], iv, sh), 0.0f);
            }
    }
    __syncthreads();
    float* yo = y2t + ((size_t)n * 2048 + t0 + tid) * 32;
#pragma unroll
    for (int j = 0; j < 8; ++j)
        *(float4*)(yo + j * 4) = *(const float4*)&sm.tr[tid * 36 + j * 4];
}

// ---------------------------------------------------------------------------
// K3+CE fused (v3, unchanged from R4): upsample2(y2t) -> conv3 + bias,
// transposed store; CE partial sum + valid flags from register-resident
// x0..x2; no fences (finalization via separate 1-block dispatch).
__global__ __launch_bounds__(256, 2) void k3_ce(
    const float* __restrict__ y2t, const float* __restrict__ w3,
    const float* __restrict__ bias, const float* __restrict__ tg,
    float* __restrict__ out, float* lacc)
{
    const int tid = threadIdx.x;
    const int t0 = blockIdx.x * 256;
    const int n  = blockIdx.y;

    __shared__ float us[32 * 321];
    __shared__ float wsh[288];
    __shared__ float wsum[4];
    __shared__ int snz[4];

    for (int idx = tid; idx < 288; idx += 256) wsh[idx] = w3[idx];

    const float* yn = y2t + (size_t)n * 2048 * 32;
    for (int idx = tid; idx < 1280; idx += 256) {
        int r = idx >> 2, gq = idx & 3;
        int u = reflect_idx(t0 - 32 + r, 4096);
        float src = fmaxf((float)u * 0.5f - 0.25f, 0.0f);
        int i0 = (int)src;
        float wl = src - (float)i0;
        int i1 = i0 + 1 > 2047 ? 2047 : i0 + 1;
        const float* p0 = yn + (size_t)i0 * 32 + gq * 8;
        const float* p1 = yn + (size_t)i1 * 32 + gq * 8;
        float4 a0 = *(const float4*)p0;
        float4 a1 = *(const float4*)(p0 + 4);
        float4 b0 = *(const float4*)p1;
        float4 b1 = *(const float4*)(p1 + 4);
        float v[8];
        v[0] = a0.x + wl * (b0.x - a0.x); v[1] = a0.y + wl * (b0.y - a0.y);
        v[2] = a0.z + wl * (b0.z - a0.z); v[3] = a0.w + wl * (b0.w - a0.w);
        v[4] = a1.x + wl * (b1.x - a1.x); v[5] = a1.y + wl * (b1.y - a1.y);
        v[6] = a1.z + wl * (b1.z - a1.z); v[7] = a1.w + wl * (b1.w - a1.w);
#pragma unroll
        for (int j = 0; j < 8; ++j)
            us[(gq * 8 + j) * 321 + r] = v[j];
    }
    __syncthreads();

    float a0 = 0.0f, a1 = 0.0f, a2 = 0.0f;
#pragma unroll 8
    for (int ci = 0; ci < 32; ++ci) {
        float x0 = us[ci * 321 + tid];
        float x1 = us[ci * 321 + tid + 32];
        float x2 = us[ci * 321 + tid + 64];
        a0 = fmaf(wsh[(0 * 32 + ci) * 3 + 0], x0, a0);
        a0 = fmaf(wsh[(0 * 32 + ci) * 3 + 1], x1, a0);
        a0 = fmaf(wsh[(0 * 32 + ci) * 3 + 2], x2, a0);
        a1 = fmaf(wsh[(1 * 32 + ci) * 3 + 0], x0, a1);
        a1 = fmaf(wsh[(1 * 32 + ci) * 3 + 1], x1, a1);
        a1 = fmaf(wsh[(1 * 32 + ci) * 3 + 2], x2, a1);
        a2 = fmaf(wsh[(2 * 32 + ci) * 3 + 0], x0, a2);
        a2 = fmaf(wsh[(2 * 32 + ci) * 3 + 1], x1, a2);
        a2 = fmaf(wsh[(2 * 32 + ci) * 3 + 2], x2, a2);
    }
    int b = n >> 2, s = n & 3;
    int t = t0 + tid;
    size_t ob = ((size_t)(b * 3) * 4096 + t) * 4 + s;
    float x0 = a0 + bias[0];
    float x1 = a1 + bias[1];
    float x2 = a2 + bias[2];
    out[ob]         = x0;
    out[ob + 16384] = x1;
    out[ob + 32768] = x2;

    // CE from registers (identical math to the original k4b pass)
    float mx = fmaxf(x0, fmaxf(x1, x2));
    float e0 = expf(x0 - mx), e1 = expf(x1 - mx), e2 = expf(x2 - mx);
    float lse = mx + logf(e0 + e1 + e2);
    float g0 = tg[ob], g1 = tg[ob + 16384], g2 = tg[ob + 32768];
    float v = g0 * (lse - x0) + g1 * (lse - x1) + g2 * (lse - x2);
    bool nz = (g0 != 0.0f) | (g1 != 0.0f) | (g2 != 0.0f);

    for (int off = 32; off > 0; off >>= 1) v += __shfl_down(v, off);
    unsigned long long m = __ballot(nz);
    int lane = tid & 63, wid = tid >> 6;
    if (lane == 0) { wsum[wid] = v; snz[wid] = (m != 0ull); }
    __syncthreads();
    if (tid == 0) {
        atomicAdd(lacc, wsum[0] + wsum[1] + wsum[2] + wsum[3]);
        if (snz[0] | snz[1] | snz[2] | snz[3])
            atomicOr((int*)lacc + 8 + n, 1);            // n == b*4 + s
    }
}

// K4c: loss = sum / (num_valid * T)  (separate dispatch = free global sync)
__global__ void k4c_final(const float* lacc, float* out) {
    if (threadIdx.x == 0) {
        float sum = lacc[0];
        const int* vf = (const int*)lacc + 8;
        int num = 0;
#pragma unroll
        for (int j = 0; j < 64; ++j) num += (vf[j] != 0);
        out[786432] = sum / ((float)num * 4096.0f);
    }
}

// ---------------------------------------------------------------------------
extern "C" void kernel_launch(void* const* d_in, const int* in_sizes, int n_in,
                              void* d_out, int out_size, void* d_ws, size_t ws_size,
                              hipStream_t stream) {
    (void)in_sizes; (void)n_in; (void)out_size;
    const float* fusion  = (const float*)d_in[0];
    const float* targets = (const float*)d_in[1];
    const float* w1  = (const float*)d_in[2];
    const float* g1  = (const float*)d_in[3];
    const float* be1 = (const float*)d_in[4];
    const float* mn1 = (const float*)d_in[5];
    const float* vr1 = (const float*)d_in[6];
    const float* w2  = (const float*)d_in[7];
    const float* g2  = (const float*)d_in[8];
    const float* be2 = (const float*)d_in[9];
    const float* mn2 = (const float*)d_in[10];
    const float* vr2 = (const float*)d_in[11];
    const float* w3  = (const float*)d_in[12];
    const float* b3  = (const float*)d_in[13];
    float* out = (float*)d_out;

    char* ws = (char*)d_ws;
    unsigned short* y1t = (unsigned short*)ws;              // 33,554,432 B
    unsigned short* xb  = (unsigned short*)(ws + 33554432); // 16 or 64 MB
    float* y2t = (float*)(ws + 33554432);                   // 16 MB, aliases xb

    const bool single = ws_size >= 101500000ull;
    size_t woff = single ? (33554432ull + 67108864ull) : (33554432ull + 16777216ull);
    unsigned short* wb  = (unsigned short*)(ws + woff);            // 786,432 B
    unsigned short* w2b = (unsigned short*)(ws + woff + 786432);   //  49,152 B
    float* lacc = (float*)(ws + woff + 786432 + 49152);            //     512 B

    if (single) {
        kprep_xt<<<dim3(16, 8, 64), 256, 0, stream>>>(fusion, w1, w2, xb, wb, w2b, lacc, 0);
        k1_mfma<<<dim3(16, 64), 256, 0, stream>>>(xb, wb, g1, be1, mn1, vr1, y1t, 0);
    } else {
        for (int r = 0; r < 4; ++r) {
            kprep_xt<<<dim3(16, 8, 16), 256, 0, stream>>>(fusion, w1, w2, xb, wb, w2b, lacc, r * 16);
            k1_mfma<<<dim3(16, 16), 256, 0, stream>>>(xb, wb, g1, be1, mn1, vr1, y1t, r * 16);
        }
    }
    k2_mfma<<<dim3(8, 64), 256, 0, stream>>>(y1t, w2b, g2, be2, mn2, vr2, y2t);
    k3_ce<<<dim3(16, 64), 256, 0, stream>>>(y2t, w3, b3, targets, out, lacc);
    k4c_final<<<1, 64, 0, stream>>>(lacc, out);
}

// Round 6
// 333.463 us; speedup vs baseline: 1.2174x; 1.0280x over previous
//
#include <hip/hip_runtime.h>
#include <hip/hip_bf16.h>

#define DEV static __device__ __forceinline__

typedef short bf16x8_t __attribute__((ext_vector_type(8)));
typedef float f32x4 __attribute__((ext_vector_type(4)));

#define GLDS16(gp, lp) __builtin_amdgcn_global_load_lds( \
    (const __attribute__((address_space(1))) void*)(gp), \
    (__attribute__((address_space(3))) void*)(lp), 16, 0, 0)

DEV int reflect_idx(int q, int L) {
    q = q < 0 ? -q : q;
    q = q >= L ? 2 * L - 2 - q : q;
    return q;
}

DEV unsigned short f2bf(float f) {
    unsigned int b = __float_as_uint(f);
    unsigned int r = (b + 0x7FFFu + ((b >> 16) & 1u)) >> 16;
    return (unsigned short)r;
}
DEV float bf2f(unsigned short u) {
    return __uint_as_float(((unsigned int)u) << 16);
}

// ---------------------------------------------------------------------------
// Fused prep + transpose (v2, proven R2/R4/R5):
__global__ __launch_bounds__(256) void kprep_xt(
        const float* __restrict__ x, const float* __restrict__ w1,
        const float* __restrict__ w2, unsigned short* __restrict__ xb,
        unsigned short* __restrict__ wb, unsigned short* __restrict__ w2b,
        float* lacc, int n0) {
    const int tid = threadIdx.x;

    if (n0 == 0) {
        int bid = (blockIdx.z * gridDim.y + blockIdx.y) * gridDim.x + blockIdx.x;
        int g = bid * 256 + tid;
        if (g < 393216) {
            int kk = g >> 17;
            int rem = g & 131071;
            int co = rem >> 9;
            int ci = rem & 511;
            wb[g] = f2bf(w1[(co * 512 + ci) * 3 + kk]);
        } else if (g < 417792) {
            int j = g - 393216;
            int ci = j & 255;
            int co = (j >> 8) & 31;
            int kk = j >> 13;
            w2b[j] = f2bf(w2[(co * 256 + ci) * 3 + kk]);
        }
        if (g < 128) lacc[g] = 0.0f;
    }

    __shared__ float ls[64][65];
    const int t0 = blockIdx.x * 64, ci0 = blockIdx.y * 64;
    const int n = n0 + blockIdx.z;
    const float* xp = x + ((size_t)n * 512 + ci0) * 1024 + t0;

    float4 v[4];
#pragma unroll
    for (int i = 0; i < 4; ++i) {
        int idx = tid + i * 256;
        int r = idx >> 4, c4 = (idx & 15) * 4;
        v[i] = *(const float4*)(xp + r * 1024 + c4);
    }
#pragma unroll
    for (int i = 0; i < 4; ++i) {
        int idx = tid + i * 256;
        int r = idx >> 4, c4 = (idx & 15) * 4;
        ls[r][c4] = v[i].x; ls[r][c4 + 1] = v[i].y;
        ls[r][c4 + 2] = v[i].z; ls[r][c4 + 3] = v[i].w;
    }
    __syncthreads();
    unsigned short* xo = xb + ((size_t)blockIdx.z * 1024 + t0) * 512 + ci0;
#pragma unroll
    for (int p = 0; p < 2; ++p) {
        int trow = (tid >> 3) + p * 32;
        int cj = (tid & 7) * 8;
        unsigned short pk[8];
#pragma unroll
        for (int j = 0; j < 8; ++j) pk[j] = f2bf(ls[cj + j][trow]);
        *(uint4*)(xo + (size_t)trow * 512 + cj) = *(const uint4*)pk;
    }
}

// ---------------------------------------------------------------------------
// K1 v8: tap-reuse. Same PROVEN sync protocol as v5/v7 (__syncthreads drain
// per interval, dbuf issue-after-barrier), same 4 blocks/CU, but intervals
// are now ci-major: interval c -> (chunk=c/3, kk=c%3). The A-tile is staged
// ONCE per ci-chunk with a +-8-row halo (144 rows, reflect at staging) and
// read at row offset +8*kk for each tap; only B (weights) stages per
// interval. Kills the 3x A HBM re-fetch (R4: FETCH 198MB = 3x xb).
// Swizzle check: (row+8kk)>>1 & 3 == row>>1 & 3 (4kk = 0 mod 4), so the
// q' = q ^ ((row>>1)&3) staging swizzle and atom = qd ^ ((tq>>1)&3) read
// slot are tap-independent.
// LDS: A 2x4608 + B 2x4096 = 17408 shorts (34816 B); epilogue [128][136]
// aliases the whole region.
__global__ __launch_bounds__(256, 4) void k1_mfma(
    const unsigned short* __restrict__ xb, const unsigned short* __restrict__ wb,
    const float* __restrict__ g, const float* __restrict__ be,
    const float* __restrict__ mn, const float* __restrict__ vr,
    unsigned short* __restrict__ y1t, int n0)
{
    const int tid  = threadIdx.x;
    const int lane = tid & 63;
    const int w    = tid >> 6;
    const int tw   = w >> 1;
    const int cw   = w & 1;
    const int tq   = lane & 15;
    const int qd   = lane >> 4;
    const int t0   = (blockIdx.x & 7) * 128;
    const int cb   = blockIdx.x >> 3;
    const int nr   = blockIdx.y;
    const int n    = n0 + nr;

    __shared__ unsigned short smem[17408];

    // B staging lane slots (proven swizzle q' = q ^ ((row>>1)&3))
    const int rl0 = tid >> 2;
    const int rl1 = 64 + (tid >> 2);
    const int q0  = (tid & 3) ^ ((rl0 >> 1) & 3);
    const int q1  = (tid & 3) ^ ((rl1 >> 1) & 3);
    const unsigned short* wp0 = wb + (size_t)(cb * 128 + rl0) * 512 + q0 * 8;
    const unsigned short* wp1 = wb + (size_t)(cb * 128 + rl1) * 512 + q1 * 8;

    // A staging: 144 rows (logical t0-8 .. t0+135, reflected) x 32 ci/chunk.
    // 576 slots of 16B = rounds {tid, 256+tid, 512+tid(tid<64)}.
    // Row of round rd: r = rd*64 + (tid>>2); quad = (tid&3) ^ ((r>>1)&3),
    // and (r>>1)&3 = (tid>>3)&3 for all rounds (rd*32 = 0 mod 4).
    const unsigned short* xn = xb + (size_t)nr * 1024 * 512;
    const int qA = (tid & 3) ^ ((tid >> 3) & 3);
    int arA[3];
#pragma unroll
    for (int rd = 0; rd < 3; ++rd) {
        int r = rd * 64 + (tid >> 2);
        arA[rd] = reflect_idx(t0 + r - 8, 1024) * 512 + qA * 8;
    }

    const int atom = qd ^ ((tq >> 1) & 3);

    f32x4 acc[4][4];
#pragma unroll
    for (int a = 0; a < 4; ++a)
#pragma unroll
        for (int b = 0; b < 4; ++b) acc[a][b] = (f32x4){0.f, 0.f, 0.f, 0.f};

#define K1A(ch) do { \
    const int ao_ = ((ch) & 1) * 4608; \
    GLDS16(xn + arA[0] + (ch) * 32, &smem[ao_ + tid * 8]); \
    GLDS16(xn + arA[1] + (ch) * 32, &smem[ao_ + 2048 + tid * 8]); \
    if (tid < 64) GLDS16(xn + arA[2] + (ch) * 32, &smem[ao_ + 4096 + tid * 8]); \
} while (0)

#define K1B(i) do { \
    const int kk_ = (i) % 3; const int ch_ = (i) / 3; \
    const int bo_ = 9216 + ((i) & 1) * 4096; \
    GLDS16(wp0 + (size_t)kk_ * 131072 + ch_ * 32, &smem[bo_ + tid * 8]); \
    GLDS16(wp1 + (size_t)kk_ * 131072 + ch_ * 32, &smem[bo_ + 2048 + tid * 8]); \
} while (0)

    // prologue: A(chunk 0) + B(interval 0)
    K1A(0);
    K1B(0);

#pragma unroll
    for (int c = 0; c < 48; ++c) {
        __syncthreads();   // vmcnt0 drain here — v5 protocol
        if (c < 47) K1B(c + 1);
        if ((c % 3) == 2 && c < 45) K1A(c / 3 + 1);
        const int kk = c % 3;
        const int ab = ((c / 3) & 1) * 4608;
        const int bb = 9216 + (c & 1) * 4096;
        bf16x8_t Af[4], Bf[4];
#pragma unroll
        for (int ts = 0; ts < 4; ++ts)
            Af[ts] = *(const bf16x8_t*)&smem[ab + (tw * 64 + ts * 16 + tq + 8 * kk) * 32 + atom * 8];
#pragma unroll
        for (int cs = 0; cs < 4; ++cs)
            Bf[cs] = *(const bf16x8_t*)&smem[bb + (cw * 64 + cs * 16 + tq) * 32 + atom * 8];
#pragma unroll
        for (int ts = 0; ts < 4; ++ts)
#pragma unroll
            for (int cs = 0; cs < 4; ++cs)
                acc[ts][cs] = __builtin_amdgcn_mfma_f32_16x16x32_bf16(
                    Af[ts], Bf[cs], acc[ts][cs], 0, 0, 0);
    }
#undef K1A
#undef K1B

    // epilogue: bn + relu -> bf16 -> LDS transpose [128t][128co] (stride 136)
    __syncthreads();
#pragma unroll
    for (int cs = 0; cs < 4; ++cs) {
        int col = cw * 64 + cs * 16 + tq;
        int co  = cb * 128 + col;
        float iv = g[co] / sqrtf(vr[co] + 1e-5f);
        float sh = be[co] - mn[co] * iv;
#pragma unroll
        for (int ts = 0; ts < 4; ++ts)
#pragma unroll
            for (int rg = 0; rg < 4; ++rg)
                smem[(tw * 64 + ts * 16 + qd * 4 + rg) * 136 + col] =
                    f2bf(fmaxf(fmaf(acc[ts][cs][rg], iv, sh), 0.0f));
    }
    __syncthreads();
    const int srow = tid >> 4, sseg = tid & 15;
#pragma unroll
    for (int p = 0; p < 8; ++p) {
        int row = p * 16 + srow;
        unsigned short* yp = y1t + ((size_t)n * 1024 + t0 + row) * 256 + cb * 128 + sseg * 8;
        *(uint4*)yp = *(const uint4*)&smem[row * 136 + sseg * 8];
    }
}

// ---------------------------------------------------------------------------
// K2 v2 (unchanged): upsample2(y1t) -> conv2 via bf16 MFMA, ping-pong staging.
__global__ __launch_bounds__(256, 2) void k2_mfma(
    const unsigned short* __restrict__ y1t, const unsigned short* __restrict__ w2b,
    const float* __restrict__ g, const float* __restrict__ be,
    const float* __restrict__ mn, const float* __restrict__ vr,
    float* __restrict__ y2t)
{
    const int tid  = threadIdx.x;
    const int lane = tid & 63;
    const int w    = tid >> 6;
    const int tq   = lane & 15;
    const int qd   = lane >> 4;
    const int t0   = blockIdx.x * 256;
    const int n    = blockIdx.y;

    __shared__ union SM {
        unsigned short us[2][288 * 40];   // 46080 B
        float tr[256 * 36];               // 36864 B (aliases, used after final sync)
    } sm;

    f32x4 acc[4][2];
#pragma unroll
    for (int a = 0; a < 4; ++a)
#pragma unroll
        for (int b = 0; b < 2; ++b) acc[a][b] = (f32x4){0.f, 0.f, 0.f, 0.f};

    const unsigned short* yn = y1t + (size_t)n * 1024 * 256;

    auto stage = [&](int ch, int buf) {
        const int ci0 = ch * 32;
        for (int idx = tid; idx < 1152; idx += 256) {
            int r = idx >> 2, gq = idx & 3;
            int u = reflect_idx(t0 - 16 + r, 2048);
            float src = fmaxf((float)u * 0.5f - 0.25f, 0.0f);
            int i0 = (int)src;
            float wl = src - (float)i0;
            int i1 = i0 + 1 > 1023 ? 1023 : i0 + 1;
            const unsigned short* p0 = yn + (size_t)i0 * 256 + ci0 + gq * 8;
            const unsigned short* p1 = yn + (size_t)i1 * 256 + ci0 + gq * 8;
            uint4 ua = *(const uint4*)p0;
            uint4 ub = *(const uint4*)p1;
            const unsigned short* sa = (const unsigned short*)&ua;
            const unsigned short* sb = (const unsigned short*)&ub;
            unsigned short pk[8];
#pragma unroll
            for (int j = 0; j < 8; ++j) {
                float a = bf2f(sa[j]);
                float b = bf2f(sb[j]);
                pk[j] = f2bf(a + wl * (b - a));
            }
            *(uint4*)&sm.us[buf][r * 40 + gq * 8] = *(const uint4*)pk;
        }
    };

    stage(0, 0);
    for (int ch = 0; ch < 8; ++ch) {
        const int buf = ch & 1;
        __syncthreads();   // buf staged; prev chunk's readers of buf^1 done
        if (ch < 7) stage(ch + 1, buf ^ 1);

        const int ci0 = ch * 32;
        bf16x8_t Bf[2][3];
#pragma unroll
        for (int cs = 0; cs < 2; ++cs)
#pragma unroll
            for (int kk = 0; kk < 3; ++kk)
                Bf[cs][kk] = *(const bf16x8_t*)(w2b +
                    ((size_t)(kk * 32 + cs * 16 + tq)) * 256 + ci0 + qd * 8);

        bf16x8_t Af[6];
#pragma unroll
        for (int s = 0; s < 6; ++s)
            Af[s] = *(const bf16x8_t*)&sm.us[buf][(w * 64 + s * 16 + tq) * 40 + qd * 8];

#pragma unroll
        for (int ts = 0; ts < 4; ++ts)
#pragma unroll
            for (int cs = 0; cs < 2; ++cs)
#pragma unroll
                for (int kk = 0; kk < 3; ++kk)
                    acc[ts][cs] = __builtin_amdgcn_mfma_f32_16x16x32_bf16(
                        Af[ts + kk], Bf[cs][kk], acc[ts][cs], 0, 0, 0);
    }

    __syncthreads();
#pragma unroll
    for (int cs = 0; cs < 2; ++cs) {
        int co = cs * 16 + tq;
        float iv = g[co] / sqrtf(vr[co] + 1e-5f);
        float sh = be[co] - mn[co] * iv;
#pragma unroll
        for (int ts = 0; ts < 4; ++ts)
#pragma unroll
            for (int rg = 0; rg < 4; ++rg) {
                int tl = w * 64 + ts * 16 + qd * 4 + rg;
                sm.tr[tl * 36 + co] = fmaxf(fmaf(acc[ts][cs][rg], iv, sh), 0.0f);
            }
    }
    __syncthreads();
    float* yo = y2t + ((size_t)n * 2048 + t0 + tid) * 32;
#pragma unroll
    for (int j = 0; j < 8; ++j)
        *(float4*)(yo + j * 4) = *(const float4*)&sm.tr[tid * 36 + j * 4];
}

// ---------------------------------------------------------------------------
// K3+CE fused (v3, unchanged from R4/R5).
__global__ __launch_bounds__(256, 2) void k3_ce(
    const float* __restrict__ y2t, const float* __restrict__ w3,
    const float* __restrict__ bias, const float* __restrict__ tg,
    float* __restrict__ out, float* lacc)
{
    const int tid = threadIdx.x;
    const int t0 = blockIdx.x * 256;
    const int n  = blockIdx.y;

    __shared__ float us[32 * 321];
    __shared__ float wsh[288];
    __shared__ float wsum[4];
    __shared__ int snz[4];

    for (int idx = tid; idx < 288; idx += 256) wsh[idx] = w3[idx];

    const float* yn = y2t + (size_t)n * 2048 * 32;
    for (int idx = tid; idx < 1280; idx += 256) {
        int r = idx >> 2, gq = idx & 3;
        int u = reflect_idx(t0 - 32 + r, 4096);
        float src = fmaxf((float)u * 0.5f - 0.25f, 0.0f);
        int i0 = (int)src;
        float wl = src - (float)i0;
        int i1 = i0 + 1 > 2047 ? 2047 : i0 + 1;
        const float* p0 = yn + (size_t)i0 * 32 + gq * 8;
        const float* p1 = yn + (size_t)i1 * 32 + gq * 8;
        float4 a0 = *(const float4*)p0;
        float4 a1 = *(const float4*)(p0 + 4);
        float4 b0 = *(const float4*)p1;
        float4 b1 = *(const float4*)(p1 + 4);
        float v[8];
        v[0] = a0.x + wl * (b0.x - a0.x); v[1] = a0.y + wl * (b0.y - a0.y);
        v[2] = a0.z + wl * (b0.z - a0.z); v[3] = a0.w + wl * (b0.w - a0.w);
        v[4] = a1.x + wl * (b1.x - a1.x); v[5] = a1.y + wl * (b1.y - a1.y);
        v[6] = a1.z + wl * (b1.z - a1.z); v[7] = a1.w + wl * (b1.w - a1.w);
#pragma unroll
        for (int j = 0; j < 8; ++j)
            us[(gq * 8 + j) * 321 + r] = v[j];
    }
    __syncthreads();

    float a0 = 0.0f, a1 = 0.0f, a2 = 0.0f;
#pragma unroll 8
    for (int ci = 0; ci < 32; ++ci) {
        float x0 = us[ci * 321 + tid];
        float x1 = us[ci * 321 + tid + 32];
        float x2 = us[ci * 321 + tid + 64];
        a0 = fmaf(wsh[(0 * 32 + ci) * 3 + 0], x0, a0);
        a0 = fmaf(wsh[(0 * 32 + ci) * 3 + 1], x1, a0);
        a0 = fmaf(wsh[(0 * 32 + ci) * 3 + 2], x2, a0);
        a1 = fmaf(wsh[(1 * 32 + ci) * 3 + 0], x0, a1);
        a1 = fmaf(wsh[(1 * 32 + ci) * 3 + 1], x1, a1);
        a1 = fmaf(wsh[(1 * 32 + ci) * 3 + 2], x2, a1);
        a2 = fmaf(wsh[(2 * 32 + ci) * 3 + 0], x0, a2);
        a2 = fmaf(wsh[(2 * 32 + ci) * 3 + 1], x1, a2);
        a2 = fmaf(wsh[(2 * 32 + ci) * 3 + 2], x2, a2);
    }
    int b = n >> 2, s = n & 3;
    int t = t0 + tid;
    size_t ob = ((size_t)(b * 3) * 4096 + t) * 4 + s;
    float x0 = a0 + bias[0];
    float x1 = a1 + bias[1];
    float x2 = a2 + bias[2];
    out[ob]         = x0;
    out[ob + 16384] = x1;
    out[ob + 32768] = x2;

    float mx = fmaxf(x0, fmaxf(x1, x2));
    float e0 = expf(x0 - mx), e1 = expf(x1 - mx), e2 = expf(x2 - mx);
    float lse = mx + logf(e0 + e1 + e2);
    float g0 = tg[ob], g1 = tg[ob + 16384], g2 = tg[ob + 32768];
    float v = g0 * (lse - x0) + g1 * (lse - x1) + g2 * (lse - x2);
    bool nz = (g0 != 0.0f) | (g1 != 0.0f) | (g2 != 0.0f);

    for (int off = 32; off > 0; off >>= 1) v += __shfl_down(v, off);
    unsigned long long m = __ballot(nz);
    int lane = tid & 63, wid = tid >> 6;
    if (lane == 0) { wsum[wid] = v; snz[wid] = (m != 0ull); }
    __syncthreads();
    if (tid == 0) {
        atomicAdd(lacc, wsum[0] + wsum[1] + wsum[2] + wsum[3]);
        if (snz[0] | snz[1] | snz[2] | snz[3])
            atomicOr((int*)lacc + 8 + n, 1);            // n == b*4 + s
    }
}

// K4c: loss = sum / (num_valid * T)  (separate dispatch = free global sync)
__global__ void k4c_final(const float* lacc, float* out) {
    if (threadIdx.x == 0) {
        float sum = lacc[0];
        const int* vf = (const int*)lacc + 8;
        int num = 0;
#pragma unroll
        for (int j = 0; j < 64; ++j) num += (vf[j] != 0);
        out[786432] = sum / ((float)num * 4096.0f);
    }
}

// ---------------------------------------------------------------------------
extern "C" void kernel_launch(void* const* d_in, const int* in_sizes, int n_in,
                              void* d_out, int out_size, void* d_ws, size_t ws_size,
                              hipStream_t stream) {
    (void)in_sizes; (void)n_in; (void)out_size;
    const float* fusion  = (const float*)d_in[0];
    const float* targets = (const float*)d_in[1];
    const float* w1  = (const float*)d_in[2];
    const float* g1  = (const float*)d_in[3];
    const float* be1 = (const float*)d_in[4];
    const float* mn1 = (const float*)d_in[5];
    const float* vr1 = (const float*)d_in[6];
    const float* w2  = (const float*)d_in[7];
    const float* g2  = (const float*)d_in[8];
    const float* be2 = (const float*)d_in[9];
    const float* mn2 = (const float*)d_in[10];
    const float* vr2 = (const float*)d_in[11];
    const float* w3  = (const float*)d_in[12];
    const float* b3  = (const float*)d_in[13];
    float* out = (float*)d_out;

    char* ws = (char*)d_ws;
    unsigned short* y1t = (unsigned short*)ws;              // 33,554,432 B
    unsigned short* xb  = (unsigned short*)(ws + 33554432); // 16 or 64 MB
    float* y2t = (float*)(ws + 33554432);                   // 16 MB, aliases xb

    const bool single = ws_size >= 101500000ull;
    size_t woff = single ? (33554432ull + 67108864ull) : (33554432ull + 16777216ull);
    unsigned short* wb  = (unsigned short*)(ws + woff);            // 786,432 B
    unsigned short* w2b = (unsigned short*)(ws + woff + 786432);   //  49,152 B
    float* lacc = (float*)(ws + woff + 786432 + 49152);            //     512 B

    if (single) {
        kprep_xt<<<dim3(16, 8, 64), 256, 0, stream>>>(fusion, w1, w2, xb, wb, w2b, lacc, 0);
        k1_mfma<<<dim3(16, 64), 256, 0, stream>>>(xb, wb, g1, be1, mn1, vr1, y1t, 0);
    } else {
        for (int r = 0; r < 4; ++r) {
            kprep_xt<<<dim3(16, 8, 16), 256, 0, stream>>>(fusion, w1, w2, xb, wb, w2b, lacc, r * 16);
            k1_mfma<<<dim3(16, 16), 256, 0, stream>>>(xb, wb, g1, be1, mn1, vr1, y1t, r * 16);
        }
    }
    k2_mfma<<<dim3(8, 64), 256, 0, stream>>>(y1t, w2b, g2, be2, mn2, vr2, y2t);
    k3_ce<<<dim3(16, 64), 256, 0, stream>>>(y2t, w3, b3, targets, out, lacc);
    k4c_final<<<1, 64, 0, stream>>>(lacc, out);
}